// Round 5
// 350.886 us; speedup vs baseline: 1.0136x; 1.0136x over previous
//
#include <hip/hip_runtime.h>

typedef __attribute__((ext_vector_type(8))) short short8;
typedef __attribute__((ext_vector_type(4))) float floatx4;

#define B_ 2
#define S_ 2048
#define H_ 2048
#define LOG2E 1.44269504088896f

#define MFMA(a, b, c) __builtin_amdgcn_mfma_f32_16x16x32_bf16(a, b, c, 0, 0, 0)

__device__ __forceinline__ unsigned short f2bf(float f) {
    unsigned int x = __builtin_bit_cast(unsigned int, f);
    unsigned int r = x + 0x7FFFu + ((x >> 16) & 1u);
    return (unsigned short)(r >> 16);
}

__device__ __forceinline__ void gload_lds16(const unsigned short* g, unsigned short* l) {
    __builtin_amdgcn_global_load_lds(
        (const __attribute__((address_space(1))) void*)g,
        (__attribute__((address_space(3))) void*)l, 16, 0, 0);
}

// ---------------- elementwise f32 -> bf16 convert (vectorized) ---------------
__global__ __launch_bounds__(256) void conv_f2b(const float* __restrict__ in,
                                                unsigned short* __restrict__ out, int n4) {
    int i = blockIdx.x * 256 + threadIdx.x;
    if (i < n4) {
        float4 v = ((const float4*)in)[i];
        ushort4 o;
        o.x = f2bf(v.x); o.y = f2bf(v.y); o.z = f2bf(v.z); o.w = f2bf(v.w);
        ((ushort4*)out)[i] = o;
    }
}

// ---------------- tiled transpose+convert: f32 in[R][C] -> bf16 out[C][R] ----
__global__ __launch_bounds__(256) void tr_f2b(const float* __restrict__ in,
                                              unsigned short* __restrict__ out,
                                              int R, int C) {
    __shared__ unsigned short t[32][33];
    int c0 = blockIdx.x * 32, r0 = blockIdx.y * 32;
    int tx = threadIdx.x & 31, ty = threadIdx.x >> 5;  // 32 x 8
#pragma unroll
    for (int i = 0; i < 32; i += 8)
        t[ty + i][tx] = f2bf(in[(size_t)(r0 + ty + i) * C + c0 + tx]);
    __syncthreads();
#pragma unroll
    for (int i = 0; i < 32; i += 8)
        out[(size_t)(c0 + ty + i) * R + r0 + tx] = t[tx][ty + i];
}

// -------- fused Wq/Wk/Wv transpose+convert into WqkvT[3072][2048] ------------
__global__ __launch_bounds__(256) void tr_wqkv(const float* __restrict__ Wq,
                                               const float* __restrict__ Wk,
                                               const float* __restrict__ Wv,
                                               unsigned short* __restrict__ WqkvT) {
    __shared__ unsigned short t[32][33];
    int bx = blockIdx.x;  // 0..95
    const float* src; int C, c0, orow;
    if (bx < 64)      { src = Wq; C = 2048; c0 = bx * 32;        orow = bx * 32; }
    else if (bx < 80) { src = Wk; C = 512;  c0 = (bx - 64) * 32; orow = 2048 + (bx - 64) * 32; }
    else              { src = Wv; C = 512;  c0 = (bx - 80) * 32; orow = 2560 + (bx - 80) * 32; }
    int r0 = blockIdx.y * 32;
    int tx = threadIdx.x & 31, ty = threadIdx.x >> 5;
#pragma unroll
    for (int i = 0; i < 32; i += 8)
        t[ty + i][tx] = f2bf(src[(size_t)(r0 + ty + i) * C + c0 + tx]);
    __syncthreads();
#pragma unroll
    for (int i = 0; i < 32; i += 8)
        WqkvT[(size_t)(orow + ty + i) * 2048 + r0 + tx] = t[tx][ty + i];
}

// -------- bf16 tiled transpose with input pitch, batched on z ----------------
__global__ __launch_bounds__(256) void tr_bf16(const unsigned short* __restrict__ in,
                                               unsigned short* __restrict__ out,
                                               int R, int C, int ipitch,
                                               size_t ibs, size_t obs) {
    __shared__ unsigned short t[32][33];
    in += (size_t)blockIdx.z * ibs; out += (size_t)blockIdx.z * obs;
    int c0 = blockIdx.x * 32, r0 = blockIdx.y * 32;
    int tx = threadIdx.x & 31, ty = threadIdx.x >> 5;
#pragma unroll
    for (int i = 0; i < 32; i += 8)
        t[ty + i][tx] = in[(size_t)(r0 + ty + i) * ipitch + c0 + tx];
    __syncthreads();
#pragma unroll
    for (int i = 0; i < 32; i += 8)
        out[(size_t)(c0 + ty + i) * R + r0 + tx] = t[tx][ty + i];
}

// ---------------- GEMM: C[M][N] = A[M][K] x Bt[N][K]^T + bias ----------------
// bias from 3 arrays split at columns s1/s2 (pass s1=s2=1<<30 for single bias).
template <bool OUT_F32>
__global__ __launch_bounds__(256) void gemm_bt(const unsigned short* __restrict__ A,
                                               const unsigned short* __restrict__ Bt,
                                               const float* __restrict__ b0,
                                               const float* __restrict__ b1,
                                               const float* __restrict__ b2,
                                               int s1, int s2,
                                               void* __restrict__ Cv,
                                               int M, int N, int K) {
    __shared__ unsigned short As[128 * 64];
    __shared__ unsigned short Bs[128 * 64];
    const int t = threadIdx.x;
    const int lane = t & 63;
    const int wave = t >> 6;
    const int qlane = lane & 15;
    const int quad = lane >> 4;
    const int wm = (wave >> 1) * 64;
    const int wn = (wave & 1) * 64;
    const int bm = blockIdx.y * 128;
    const int bn = blockIdx.x * 128;
    const int srow = t >> 3;
    const int scc = (t & 7) * 8;
    const int gc8 = (((t & 7) ^ (2 * ((t >> 5) & 3))) * 8);
    const int rsw = 2 * (qlane >> 2);

    floatx4 acc[4][4] = {};

    for (int k0 = 0; k0 < K; k0 += 64) {
        __syncthreads();
#pragma unroll
        for (int r = 0; r < 4; ++r) {
            int row = r * 32 + srow;
            gload_lds16(A + (size_t)(bm + row) * K + k0 + gc8, &As[row * 64 + scc]);
        }
#pragma unroll
        for (int r = 0; r < 4; ++r) {
            int row = r * 32 + srow;
            gload_lds16(Bt + (size_t)(bn + row) * K + k0 + gc8, &Bs[row * 64 + scc]);
        }
        __syncthreads();
#pragma unroll
        for (int kk = 0; kk < 2; ++kk) {
            short8 a[4], b[4];
#pragma unroll
            for (int i = 0; i < 4; ++i)
                a[i] = *(const short8*)&As[(wm + i * 16 + qlane) * 64 + ((kk * 4 + quad) ^ rsw) * 8];
#pragma unroll
            for (int j = 0; j < 4; ++j)
                b[j] = *(const short8*)&Bs[(wn + j * 16 + qlane) * 64 + ((kk * 4 + quad) ^ rsw) * 8];
#pragma unroll
            for (int i = 0; i < 4; ++i)
#pragma unroll
                for (int j = 0; j < 4; ++j)
                    acc[i][j] = MFMA(a[i], b[j], acc[i][j]);
        }
    }
#pragma unroll
    for (int j = 0; j < 4; ++j) {
        int col = bn + wn + j * 16 + qlane;
        int cc = col; const float* bp = b0;
        if (col >= s2)      { bp = b2; cc = col - s2; }
        else if (col >= s1) { bp = b1; cc = col - s1; }
        float bvv = bp[cc];
#pragma unroll
        for (int i = 0; i < 4; ++i) {
            int row0 = bm + wm + i * 16 + quad * 4;
#pragma unroll
            for (int r = 0; r < 4; ++r) {
                float v = acc[i][j][r] + bvv;
                if (OUT_F32)
                    ((float*)Cv)[(size_t)(row0 + r) * N + col] = v;
                else
                    ((unsigned short*)Cv)[(size_t)(row0 + r) * N + col] = f2bf(v);
            }
        }
    }
}

// ---------------- Flash attention (128-row Q tiles, 32 rows/wave) ------------
// grid (16 qtiles, 32 heads, 2 batch) = 1024 blocks, 256 threads.
// LDS = 40KB exactly (Ks single 8K + Vts dbuf 16K + Ps 16K) -> 4 blocks/CU,
// all 1024 blocks co-resident, zero dispatch tail.
// Compute path (QK orientation, exp2+Ps store, PV, epilogue) is byte-identical
// to the proven R4/355.9us kernel. Only the STAGING SCHEDULE changed:
//   top of kt: issue V(kt+1) -> Vts[^1] (async; drains at barrier A, covered
//     by QK+exp -- the old scheme drained V with ~zero cover at barrier#1)
//   QK^T reads Ks -> exp+Ps (wave-private, lgkmcnt-ordered)
//   barrier A: all waves done reading Ks(kt); V(kt+1) landed
//   issue K(kt+1) -> Ks (async; drains at barrier B, covered by PV)
//   PV + rowsum reads Vts[cur] + own Ps slab
//   barrier B: K(kt+1) landed; Vts[cur] reads done (safe to overwrite next kt)
// Race audit: Ks is written only between A and B, read only between B and A.
// Vts[x] written one full iteration before read, visibility established at
// the intervening barrier (vmcnt(0) drain before s_barrier). Same discipline
// as the proven baseline. setprio(1) wraps both MFMA clusters (T5, +4-7%).
// Numerics: R4-proven path (fp32 fma scale inside exp2, half-up bf16 pack).
__global__ __launch_bounds__(256, 4) void attn_kernel(const unsigned short* __restrict__ qkv,
                                                      const unsigned short* __restrict__ vtb,
                                                      const float* __restrict__ mask,
                                                      unsigned short* __restrict__ ob) {
    const int qt = blockIdx.x;
    const int head = blockIdx.y;
    const int b = blockIdx.z;
    const int kvh = head >> 2;
    const int qcol = head * 64;
    const int kcol = 2048 + kvh * 64;   // K slice inside qkv row
    const int vch = kvh * 64;           // Vt channel base
    const int q0 = qt * 128;
    const int t = threadIdx.x;
    const int lane = t & 63;
    const int wave = t >> 6;
    const int qlane = lane & 15;
    const int quad = lane >> 4;
    const int wr = wave * 32;

    __shared__ unsigned short Ks[64 * 64];      //  8 KB (single)
    __shared__ unsigned short Vts[2][64 * 64];  // 16 KB (double buffer)
    __shared__ unsigned short Ps[128 * 64];     // 16 KB (wave-private slabs)

    const int gc8 = (((t & 7) ^ (2 * ((t >> 5) & 3))) * 8);  // swizzled global chunk
    const int rsw = 2 * (qlane >> 2);                        // read-side swizzle
    const float scale2 = 0.125f * LOG2E;

    const unsigned short* vbase = vtb + (size_t)(b * 512 + vch) * S_;
    const float* mbase = mask + (size_t)b * S_;

    // Q fragments straight from global (16B contiguous per lane)
    short8 aq[2][2];
#pragma unroll
    for (int mi = 0; mi < 2; ++mi)
#pragma unroll
        for (int kk = 0; kk < 2; ++kk)
            aq[mi][kk] = *(const short8*)(qkv +
                (size_t)(b * S_ + q0 + wr + mi * 16 + qlane) * 3072 + qcol + kk * 32 + quad * 8);

    // prologue: stage K(0) into Ks and V(0) into Vts[0]
    {
        int row = t >> 3;
#pragma unroll
        for (int i = 0; i < 2; ++i) {
            int rr = row + 32 * i;
            gload_lds16(qkv + (size_t)(b * S_ + rr) * 3072 + kcol + gc8,
                        &Ks[(rr * 8 + (t & 7)) * 8]);
            gload_lds16(vbase + (size_t)rr * S_ + gc8,
                        &Vts[0][(rr * 8 + (t & 7)) * 8]);
        }
    }

    // ones B-fragment: B[k][0]=1 -> row-sum lands in column 0 of osum
    short8 ones;
    {
        short v = (qlane == 0) ? (short)0x3F80 : (short)0;
        ones = (short8){v, v, v, v, v, v, v, v};
    }

    floatx4 o[2][4] = {};
    floatx4 osum[2] = {};

    __syncthreads();

    for (int kt = 0; kt < 32; ++kt) {
        const int cur = kt & 1;

        // ---- (1) issue V(kt+1) into Vts[^1] (async; drains at barrier A,
        //      covered by QK + exp below) ----
        if (kt < 31) {
            const int nxt = cur ^ 1;
            int kn = (kt + 1) * 64;
            int row = t >> 3;
#pragma unroll
            for (int i = 0; i < 2; ++i) {
                int rr = row + 32 * i;
                gload_lds16(vbase + (size_t)rr * S_ + kn + gc8,
                            &Vts[nxt][(rr * 8 + (t & 7)) * 8]);
            }
        }
        // ---- (2) mask values for this kt ----
        float m2[4];
#pragma unroll
        for (int j = 0; j < 4; ++j)
            m2[j] = mbase[kt * 64 + j * 16 + qlane] * LOG2E;

        // ---- (3) QK^T: 32 q-rows x 64 keys per wave (reads Ks) ----
        floatx4 s[2][4] = {};
        __builtin_amdgcn_s_setprio(1);
#pragma unroll
        for (int j = 0; j < 4; ++j) {
            short8 bk0 = *(const short8*)&Ks[(j * 16 + qlane) * 64 + ((0 + quad) ^ rsw) * 8];
            short8 bk1 = *(const short8*)&Ks[(j * 16 + qlane) * 64 + ((4 + quad) ^ rsw) * 8];
#pragma unroll
            for (int mi = 0; mi < 2; ++mi) {
                s[mi][j] = MFMA(aq[mi][0], bk0, s[mi][j]);
                s[mi][j] = MFMA(aq[mi][1], bk1, s[mi][j]);
            }
        }
        __builtin_amdgcn_s_setprio(0);

        // ---- (4) exp2 + P store (half-up round, hi16 store, swizzled) ----
#pragma unroll
        for (int mi = 0; mi < 2; ++mi)
#pragma unroll
            for (int j = 0; j < 4; ++j) {
                int ebase = (wr + mi * 16 + quad * 4) * 64 + 16 * (j ^ quad) + qlane;
#pragma unroll
                for (int r = 0; r < 4; ++r) {
                    float p = __builtin_amdgcn_exp2f(s[mi][j][r] * scale2 + m2[j]);
                    unsigned int u = __builtin_bit_cast(unsigned int, p) + 0x8000u;
                    Ps[ebase + r * 64] = (unsigned short)(u >> 16);
                }
            }

        // ---- barrier A: all waves done reading Ks(kt); V(kt+1) landed ----
        __syncthreads();

        // ---- (5) issue K(kt+1) into Ks (async; drains at barrier B,
        //      covered by PV below) ----
        if (kt < 31) {
            int kn = (kt + 1) * 64;
            int row = t >> 3;
#pragma unroll
            for (int i = 0; i < 2; ++i) {
                int rr = row + 32 * i;
                gload_lds16(qkv + (size_t)(b * S_ + kn + rr) * 3072 + kcol + gc8,
                            &Ks[(rr * 8 + (t & 7)) * 8]);
            }
        }

        // ---- (6) PV + row-sum: V from Vts[cur]; P a-frags from own slab ----
        __builtin_amdgcn_s_setprio(1);
#pragma unroll
        for (int kk = 0; kk < 2; ++kk) {
            short8 ap[2];
#pragma unroll
            for (int mi = 0; mi < 2; ++mi)
                ap[mi] = *(const short8*)&Ps[(wr + mi * 16 + qlane) * 64 + ((kk * 4 + quad) ^ rsw) * 8];
#pragma unroll
            for (int j2 = 0; j2 < 4; ++j2) {
                short8 bv = *(const short8*)&Vts[cur][(j2 * 16 + qlane) * 64 + ((kk * 4 + quad) ^ rsw) * 8];
#pragma unroll
                for (int mi = 0; mi < 2; ++mi)
                    o[mi][j2] = MFMA(ap[mi], bv, o[mi][j2]);
            }
#pragma unroll
            for (int mi = 0; mi < 2; ++mi)
                osum[mi] = MFMA(ap[mi], ones, osum[mi]);
        }
        __builtin_amdgcn_s_setprio(0);

        // ---- barrier B: K(kt+1) landed; Vts[cur] reads complete ----
        __syncthreads();
    }

    // ---- epilogue: broadcast row-sum (col 0 of osum), normalize, store ----
#pragma unroll
    for (int mi = 0; mi < 2; ++mi)
#pragma unroll
        for (int r = 0; r < 4; ++r) {
            float sm = __shfl(osum[mi][r], quad * 16, 64);
            float inv = 1.0f / sm;
            int row = q0 + wr + mi * 16 + quad * 4 + r;
#pragma unroll
            for (int j2 = 0; j2 < 4; ++j2)
                ob[(size_t)(b * S_ + row) * H_ + qcol + j2 * 16 + qlane] = f2bf(o[mi][j2][r] * inv);
        }
}

extern "C" void kernel_launch(void* const* d_in, const int* in_sizes, int n_in,
                              void* d_out, int out_size, void* d_ws, size_t ws_size,
                              hipStream_t stream) {
    const float* x    = (const float*)d_in[0];
    const float* mask = (const float*)d_in[1];
    const float* Wq   = (const float*)d_in[2];
    const float* bq   = (const float*)d_in[3];
    const float* Wk   = (const float*)d_in[4];
    const float* bk   = (const float*)d_in[5];
    const float* Wv   = (const float*)d_in[6];
    const float* bv   = (const float*)d_in[7];
    const float* Wo   = (const float*)d_in[8];
    const float* bo   = (const float*)d_in[9];
    float* out = (float*)d_out;

    // workspace (bf16 elems), 56 MB total:
    //   x_bf [4096][2048] (later: attn out), qkv [4096][3072],
    //   vt [2][512][2048], WqkvT [3072][2048] (later: WoT [2048][2048])
    unsigned short* ws = (unsigned short*)d_ws;
    unsigned short* x_bf   = ws;
    unsigned short* qkv    = x_bf + (size_t)4096 * 2048;
    unsigned short* vt_buf = qkv + (size_t)4096 * 3072;
    unsigned short* WqkvT  = vt_buf + (size_t)2 * 512 * 2048;
    unsigned short* WoT    = WqkvT;           // aliased: Wo transposed after QKV GEMM
    unsigned short* a_buf  = x_bf;            // aliased: x consumed by QKV GEMM

    const int BIG = 1 << 30;
    dim3 blk(256);
    // x -> bf16
    conv_f2b<<<dim3(4096 * 2048 / 4 / 256), blk, 0, stream>>>(x, x_bf, 4096 * 2048 / 4);
    // Wq|Wk|Wv -> WqkvT [3072][2048] (one launch)
    tr_wqkv<<<dim3(96, 64), blk, 0, stream>>>(Wq, Wk, Wv, WqkvT);
    // fused QKV projection: [4096][2048] x [3072][2048]^T -> qkv [4096][3072]
    gemm_bt<false><<<dim3(24, 32), blk, 0, stream>>>(x_bf, WqkvT, bq, bk, bv, 2048, 2560,
                                                     qkv, 4096, 3072, 2048);
    // Wo -> WoT (into WqkvT's space, now dead)
    tr_f2b<<<dim3(64, 64), blk, 0, stream>>>(Wo, WoT, 2048, 2048);
    // per-batch V transpose: qkv[b][s][2560..3071] -> vt [b][512][S]
    tr_bf16<<<dim3(16, 64, 2), blk, 0, stream>>>(qkv + 2560, vt_buf, 2048, 512, 3072,
                                                 (size_t)2048 * 3072, (size_t)512 * 2048);
    // attention (writes a_buf = x_bf)
    attn_kernel<<<dim3(16, 32, 2), blk, 0, stream>>>(qkv, vt_buf, mask, a_buf);
    // output projection (f32 out)
    gemm_bt<true><<<dim3(16, 32), blk, 0, stream>>>(a_buf, WoT, bo, bo, bo, BIG, BIG,
                                                    out, 4096, 2048, 2048);
}

// Round 6
// 347.602 us; speedup vs baseline: 1.0232x; 1.0094x over previous
//
#include <hip/hip_runtime.h>

typedef __attribute__((ext_vector_type(8))) short short8;
typedef __attribute__((ext_vector_type(4))) float floatx4;
typedef __attribute__((ext_vector_type(4))) unsigned int uintx4;

#define B_ 2
#define S_ 2048
#define H_ 2048
#define LOG2E 1.44269504088896f

#define MFMA(a, b, c) __builtin_amdgcn_mfma_f32_16x16x32_bf16(a, b, c, 0, 0, 0)

__device__ __forceinline__ unsigned short f2bf(float f) {
    unsigned int x = __builtin_bit_cast(unsigned int, f);
    unsigned int r = x + 0x7FFFu + ((x >> 16) & 1u);
    return (unsigned short)(r >> 16);
}

__device__ __forceinline__ void gload_lds16(const unsigned short* g, unsigned short* l) {
    __builtin_amdgcn_global_load_lds(
        (const __attribute__((address_space(1))) void*)g,
        (__attribute__((address_space(3))) void*)l, 16, 0, 0);
}

// ---------------- elementwise f32 -> bf16 convert (vectorized) ---------------
__global__ __launch_bounds__(256) void conv_f2b(const float* __restrict__ in,
                                                unsigned short* __restrict__ out, int n4) {
    int i = blockIdx.x * 256 + threadIdx.x;
    if (i < n4) {
        float4 v = ((const float4*)in)[i];
        ushort4 o;
        o.x = f2bf(v.x); o.y = f2bf(v.y); o.z = f2bf(v.z); o.w = f2bf(v.w);
        ((ushort4*)out)[i] = o;
    }
}

// ---------------- tiled transpose+convert: f32 in[R][C] -> bf16 out[C][R] ----
__global__ __launch_bounds__(256) void tr_f2b(const float* __restrict__ in,
                                              unsigned short* __restrict__ out,
                                              int R, int C) {
    __shared__ unsigned short t[32][33];
    int c0 = blockIdx.x * 32, r0 = blockIdx.y * 32;
    int tx = threadIdx.x & 31, ty = threadIdx.x >> 5;  // 32 x 8
#pragma unroll
    for (int i = 0; i < 32; i += 8)
        t[ty + i][tx] = f2bf(in[(size_t)(r0 + ty + i) * C + c0 + tx]);
    __syncthreads();
#pragma unroll
    for (int i = 0; i < 32; i += 8)
        out[(size_t)(c0 + ty + i) * R + r0 + tx] = t[tx][ty + i];
}

// -------- fused Wq/Wk/Wv transpose+convert into WqkvT[3072][2048] ------------
__global__ __launch_bounds__(256) void tr_wqkv(const float* __restrict__ Wq,
                                               const float* __restrict__ Wk,
                                               const float* __restrict__ Wv,
                                               unsigned short* __restrict__ WqkvT) {
    __shared__ unsigned short t[32][33];
    int bx = blockIdx.x;  // 0..95
    const float* src; int C, c0, orow;
    if (bx < 64)      { src = Wq; C = 2048; c0 = bx * 32;        orow = bx * 32; }
    else if (bx < 80) { src = Wk; C = 512;  c0 = (bx - 64) * 32; orow = 2048 + (bx - 64) * 32; }
    else              { src = Wv; C = 512;  c0 = (bx - 80) * 32; orow = 2560 + (bx - 80) * 32; }
    int r0 = blockIdx.y * 32;
    int tx = threadIdx.x & 31, ty = threadIdx.x >> 5;
#pragma unroll
    for (int i = 0; i < 32; i += 8)
        t[ty + i][tx] = f2bf(src[(size_t)(r0 + ty + i) * C + c0 + tx]);
    __syncthreads();
#pragma unroll
    for (int i = 0; i < 32; i += 8)
        WqkvT[(size_t)(orow + ty + i) * 2048 + r0 + tx] = t[tx][ty + i];
}

// -------- bf16 V transpose with key-permuted output columns ------------------
// out[channel][s'] where within each 64-key block, key s = 16j+4q+i is stored
// at column s' = 32*(j>>1) + 8q + 4*(j&1) + i. Inverse: stored col p holds key
// 16*(2*(p>>5) + ((p>>2)&1)) + 4*((p>>3)&3) + (p&3). With the attn PV B-frag
// reading stored cols kk*32+quad*8+e, slot (kk,quad,e) holds key
// 16*(2kk+(e>>2)) + 4*quad + (e&3) -- exactly the keys the swapped-QK^T
// fragment leaves lane-local, so the P A-fragment is a pure register
// rearrangement. Bijective within each 64-block; full 64B-line coverage.
__global__ __launch_bounds__(256) void tr_vperm(const unsigned short* __restrict__ in,
                                                unsigned short* __restrict__ out,
                                                int R, int C, int ipitch,
                                                size_t ibs, size_t obs) {
    __shared__ unsigned short t[32][33];
    in += (size_t)blockIdx.z * ibs; out += (size_t)blockIdx.z * obs;
    int c0 = blockIdx.x * 32, r0 = blockIdx.y * 32;
    int tx = threadIdx.x & 31, ty = threadIdx.x >> 5;
#pragma unroll
    for (int i = 0; i < 32; i += 8)
        t[ty + i][tx] = in[(size_t)(r0 + ty + i) * ipitch + c0 + tx];
    __syncthreads();
    int s = r0 + tx;
    int sl = s & 63;
    int j = sl >> 4, q = (sl >> 2) & 3, ii = sl & 3;
    int sp = (s & ~63) + ((j >> 1) << 5) + (q << 3) + ((j & 1) << 2) + ii;
#pragma unroll
    for (int i = 0; i < 32; i += 8)
        out[(size_t)(c0 + ty + i) * R + sp] = t[tx][ty + i];
}

// ---------------- GEMM: C[M][N] = A[M][K] x Bt[N][K]^T + bias ----------------
// bias from 3 arrays split at columns s1/s2 (pass s1=s2=1<<30 for single bias).
template <bool OUT_F32>
__global__ __launch_bounds__(256) void gemm_bt(const unsigned short* __restrict__ A,
                                               const unsigned short* __restrict__ Bt,
                                               const float* __restrict__ b0,
                                               const float* __restrict__ b1,
                                               const float* __restrict__ b2,
                                               int s1, int s2,
                                               void* __restrict__ Cv,
                                               int M, int N, int K) {
    __shared__ unsigned short As[128 * 64];
    __shared__ unsigned short Bs[128 * 64];
    const int t = threadIdx.x;
    const int lane = t & 63;
    const int wave = t >> 6;
    const int qlane = lane & 15;
    const int quad = lane >> 4;
    const int wm = (wave >> 1) * 64;
    const int wn = (wave & 1) * 64;
    const int bm = blockIdx.y * 128;
    const int bn = blockIdx.x * 128;
    const int srow = t >> 3;
    const int scc = (t & 7) * 8;
    const int gc8 = (((t & 7) ^ (2 * ((t >> 5) & 3))) * 8);
    const int rsw = 2 * (qlane >> 2);

    floatx4 acc[4][4] = {};

    for (int k0 = 0; k0 < K; k0 += 64) {
        __syncthreads();
#pragma unroll
        for (int r = 0; r < 4; ++r) {
            int row = r * 32 + srow;
            gload_lds16(A + (size_t)(bm + row) * K + k0 + gc8, &As[row * 64 + scc]);
        }
#pragma unroll
        for (int r = 0; r < 4; ++r) {
            int row = r * 32 + srow;
            gload_lds16(Bt + (size_t)(bn + row) * K + k0 + gc8, &Bs[row * 64 + scc]);
        }
        __syncthreads();
#pragma unroll
        for (int kk = 0; kk < 2; ++kk) {
            short8 a[4], b[4];
#pragma unroll
            for (int i = 0; i < 4; ++i)
                a[i] = *(const short8*)&As[(wm + i * 16 + qlane) * 64 + ((kk * 4 + quad) ^ rsw) * 8];
#pragma unroll
            for (int j = 0; j < 4; ++j)
                b[j] = *(const short8*)&Bs[(wn + j * 16 + qlane) * 64 + ((kk * 4 + quad) ^ rsw) * 8];
#pragma unroll
            for (int i = 0; i < 4; ++i)
#pragma unroll
                for (int j = 0; j < 4; ++j)
                    acc[i][j] = MFMA(a[i], b[j], acc[i][j]);
        }
    }
#pragma unroll
    for (int j = 0; j < 4; ++j) {
        int col = bn + wn + j * 16 + qlane;
        int cc = col; const float* bp = b0;
        if (col >= s2)      { bp = b2; cc = col - s2; }
        else if (col >= s1) { bp = b1; cc = col - s1; }
        float bvv = bp[cc];
#pragma unroll
        for (int i = 0; i < 4; ++i) {
            int row0 = bm + wm + i * 16 + quad * 4;
#pragma unroll
            for (int r = 0; r < 4; ++r) {
                float v = acc[i][j][r] + bvv;
                if (OUT_F32)
                    ((float*)Cv)[(size_t)(row0 + r) * N + col] = v;
                else
                    ((unsigned short*)Cv)[(size_t)(row0 + r) * N + col] = f2bf(v);
            }
        }
    }
}

// ---------------- Flash attention (128-row Q tiles, 32 rows/wave) ------------
// grid (16 qtiles, 32 heads, 2 batch) = 1024 blocks, 256 threads.
// LDS = 24KB (Ks single 8K + Vts dbuf 16K) -> 4 blocks/CU (grid-capped),
// all 1024 blocks co-resident, zero dispatch tail.
// STAGING SCHEDULE: byte-identical to the R5 PASSING kernel (V(kt+1) issued
// at top, drains at barrier A; K(kt+1) issued after A, drains at barrier B).
// COMPUTE: swapped QK^T -- st = MFMA(K_tile, Q_frag) gives S^T, so lane
// (qlane,quad) holds S for q-row wr+mi*16+qlane at keys 16j+4quad+r: the
// entire P row is lane-local. P never touches LDS (Ps deleted):
//   pack: half-up bf16 (EXACT baseline numerics, plain shift/or -- no cvt_pk)
//   pk[mi][j][h] = {lo: key idx 2h, hi: idx 2h+1}
//   ap[kk][mi] word w: pk[mi][2kk + (w>>1)][w&1]  (pure register rearrange)
// V's key order is pre-permuted by tr_vperm so PV B-slot (kk,quad,e) holds
// key 16(2kk+(e>>2))+4quad+(e&3) = exactly ap slot e's key. MFMA slot pairing
// A(quad,e)<->B(quad,e) is identity (proven by the baseline GEMM/PV).
// No cvt_pk, no permlane (the two instructions unverified by any passing
// kernel). If this fails numerically, the swapped-QK axiom is the R2/R3 bug.
__global__ __launch_bounds__(256, 4) void attn_kernel(const unsigned short* __restrict__ qkv,
                                                      const unsigned short* __restrict__ vtb,
                                                      const float* __restrict__ mask,
                                                      unsigned short* __restrict__ ob) {
    const int qt = blockIdx.x;
    const int head = blockIdx.y;
    const int b = blockIdx.z;
    const int kvh = head >> 2;
    const int qcol = head * 64;
    const int kcol = 2048 + kvh * 64;   // K slice inside qkv row
    const int vch = kvh * 64;           // Vt channel base
    const int q0 = qt * 128;
    const int t = threadIdx.x;
    const int lane = t & 63;
    const int wave = t >> 6;
    const int qlane = lane & 15;
    const int quad = lane >> 4;
    const int wr = wave * 32;

    __shared__ unsigned short Ks[64 * 64];      //  8 KB (single)
    __shared__ unsigned short Vts[2][64 * 64];  // 16 KB (double buffer)

    const int gc8 = (((t & 7) ^ (2 * ((t >> 5) & 3))) * 8);  // swizzled global chunk
    const int rsw = 2 * (qlane >> 2);                        // read-side swizzle
    const float scale2 = 0.125f * LOG2E;

    const unsigned short* vbase = vtb + (size_t)(b * 512 + vch) * S_;
    const float* mbase = mask + (size_t)b * S_;

    // Q fragments straight from global (16B contiguous per lane).
    // B-operand of swapped QK^T: col = q-row (qlane), k = d.
    short8 aq[2][2];
#pragma unroll
    for (int mi = 0; mi < 2; ++mi)
#pragma unroll
        for (int kk = 0; kk < 2; ++kk)
            aq[mi][kk] = *(const short8*)(qkv +
                (size_t)(b * S_ + q0 + wr + mi * 16 + qlane) * 3072 + qcol + kk * 32 + quad * 8);

    // prologue: stage K(0) into Ks and V(0) into Vts[0]
    {
        int row = t >> 3;
#pragma unroll
        for (int i = 0; i < 2; ++i) {
            int rr = row + 32 * i;
            gload_lds16(qkv + (size_t)(b * S_ + rr) * 3072 + kcol + gc8,
                        &Ks[(rr * 8 + (t & 7)) * 8]);
            gload_lds16(vbase + (size_t)rr * S_ + gc8,
                        &Vts[0][(rr * 8 + (t & 7)) * 8]);
        }
    }

    // ones B-fragment: B[k][0]=1 -> row-sum lands in column 0 of osum
    short8 ones;
    {
        short v = (qlane == 0) ? (short)0x3F80 : (short)0;
        ones = (short8){v, v, v, v, v, v, v, v};
    }

    floatx4 o[2][4] = {};
    floatx4 osum[2] = {};

    __syncthreads();

    for (int kt = 0; kt < 32; ++kt) {
        const int cur = kt & 1;

        // ---- (1) issue V(kt+1) into Vts[^1] (async; drains at barrier A) ----
        if (kt < 31) {
            const int nxt = cur ^ 1;
            int kn = (kt + 1) * 64;
            int row = t >> 3;
#pragma unroll
            for (int i = 0; i < 2; ++i) {
                int rr = row + 32 * i;
                gload_lds16(vbase + (size_t)rr * S_ + kn + gc8,
                            &Vts[nxt][(rr * 8 + (t & 7)) * 8]);
            }
        }

        // ---- (2) swapped QK^T + exp2 + pack, j-pairs to bound liveness ----
        // st[dj][mi][r] = S[key=16(jj+dj)+4quad+r][q=wr+mi*16+qlane]
        unsigned int pk[2][4][2];
#pragma unroll
        for (int jj = 0; jj < 4; jj += 2) {
            floatx4 st[2][2] = {};
            __builtin_amdgcn_s_setprio(1);
#pragma unroll
            for (int dj = 0; dj < 2; ++dj) {
                int j = jj + dj;
                short8 bk0 = *(const short8*)&Ks[(j * 16 + qlane) * 64 + ((0 + quad) ^ rsw) * 8];
                short8 bk1 = *(const short8*)&Ks[(j * 16 + qlane) * 64 + ((4 + quad) ^ rsw) * 8];
#pragma unroll
                for (int mi = 0; mi < 2; ++mi) {
                    st[dj][mi] = MFMA(bk0, aq[mi][0], st[dj][mi]);
                    st[dj][mi] = MFMA(bk1, aq[mi][1], st[dj][mi]);
                }
            }
            __builtin_amdgcn_s_setprio(0);
#pragma unroll
            for (int dj = 0; dj < 2; ++dj) {
                int j = jj + dj;
                floatx4 mv = *(const floatx4*)(mbase + kt * 64 + j * 16 + quad * 4);
#pragma unroll
                for (int mi = 0; mi < 2; ++mi)
#pragma unroll
                    for (int h = 0; h < 2; ++h) {
                        float p0 = __builtin_amdgcn_exp2f(st[dj][mi][2 * h]     * scale2 + mv[2 * h]     * LOG2E);
                        float p1 = __builtin_amdgcn_exp2f(st[dj][mi][2 * h + 1] * scale2 + mv[2 * h + 1] * LOG2E);
                        unsigned int ua = __builtin_bit_cast(unsigned int, p0) + 0x8000u;
                        unsigned int ub = __builtin_bit_cast(unsigned int, p1) + 0x8000u;
                        pk[mi][j][h] = (ua >> 16) | (ub & 0xFFFF0000u);
                    }
            }
        }

        // ---- barrier A: all waves done reading Ks(kt); V(kt+1) landed ----
        __syncthreads();

        // ---- (3) issue K(kt+1) into Ks (async; drains at barrier B) ----
        if (kt < 31) {
            int kn = (kt + 1) * 64;
            int row = t >> 3;
#pragma unroll
            for (int i = 0; i < 2; ++i) {
                int rr = row + 32 * i;
                gload_lds16(qkv + (size_t)(b * S_ + kn + rr) * 3072 + kcol + gc8,
                            &Ks[(rr * 8 + (t & 7)) * 8]);
            }
        }

        // ---- (4) PV + row-sum: P from registers, V from Vts[cur] ----
        __builtin_amdgcn_s_setprio(1);
#pragma unroll
        for (int kk = 0; kk < 2; ++kk) {
            short8 ap[2];
#pragma unroll
            for (int mi = 0; mi < 2; ++mi) {
                uintx4 u = {pk[mi][2 * kk][0], pk[mi][2 * kk][1],
                            pk[mi][2 * kk + 1][0], pk[mi][2 * kk + 1][1]};
                ap[mi] = __builtin_bit_cast(short8, u);
            }
#pragma unroll
            for (int j2 = 0; j2 < 4; ++j2) {
                short8 bv = *(const short8*)&Vts[cur][(j2 * 16 + qlane) * 64 + ((kk * 4 + quad) ^ rsw) * 8];
#pragma unroll
                for (int mi = 0; mi < 2; ++mi)
                    o[mi][j2] = MFMA(ap[mi], bv, o[mi][j2]);
            }
#pragma unroll
            for (int mi = 0; mi < 2; ++mi)
                osum[mi] = MFMA(ap[mi], ones, osum[mi]);
        }
        __builtin_amdgcn_s_setprio(0);

        // ---- barrier B: K(kt+1) landed; Vts[cur] reads complete ----
        __syncthreads();
    }

    // ---- epilogue: broadcast row-sum (col 0 of osum), normalize, store ----
#pragma unroll
    for (int mi = 0; mi < 2; ++mi)
#pragma unroll
        for (int r = 0; r < 4; ++r) {
            float sm = __shfl(osum[mi][r], quad * 16, 64);
            float inv = 1.0f / sm;
            int row = q0 + wr + mi * 16 + quad * 4 + r;
#pragma unroll
            for (int j2 = 0; j2 < 4; ++j2)
                ob[(size_t)(b * S_ + row) * H_ + qcol + j2 * 16 + qlane] = f2bf(o[mi][j2][r] * inv);
        }
}

extern "C" void kernel_launch(void* const* d_in, const int* in_sizes, int n_in,
                              void* d_out, int out_size, void* d_ws, size_t ws_size,
                              hipStream_t stream) {
    const float* x    = (const float*)d_in[0];
    const float* mask = (const float*)d_in[1];
    const float* Wq   = (const float*)d_in[2];
    const float* bq   = (const float*)d_in[3];
    const float* Wk   = (const float*)d_in[4];
    const float* bk   = (const float*)d_in[5];
    const float* Wv   = (const float*)d_in[6];
    const float* bv   = (const float*)d_in[7];
    const float* Wo   = (const float*)d_in[8];
    const float* bo   = (const float*)d_in[9];
    float* out = (float*)d_out;

    // workspace (bf16 elems), 56 MB total:
    //   x_bf [4096][2048] (later: attn out), qkv [4096][3072],
    //   vt [2][512][2048] (key-permuted within 64-blocks),
    //   WqkvT [3072][2048] (later: WoT [2048][2048])
    unsigned short* ws = (unsigned short*)d_ws;
    unsigned short* x_bf   = ws;
    unsigned short* qkv    = x_bf + (size_t)4096 * 2048;
    unsigned short* vt_buf = qkv + (size_t)4096 * 3072;
    unsigned short* WqkvT  = vt_buf + (size_t)2 * 512 * 2048;
    unsigned short* WoT    = WqkvT;           // aliased: Wo transposed after QKV GEMM
    unsigned short* a_buf  = x_bf;            // aliased: x consumed by QKV GEMM

    const int BIG = 1 << 30;
    dim3 blk(256);
    // x -> bf16
    conv_f2b<<<dim3(4096 * 2048 / 4 / 256), blk, 0, stream>>>(x, x_bf, 4096 * 2048 / 4);
    // Wq|Wk|Wv -> WqkvT [3072][2048] (one launch)
    tr_wqkv<<<dim3(96, 64), blk, 0, stream>>>(Wq, Wk, Wv, WqkvT);
    // fused QKV projection: [4096][2048] x [3072][2048]^T -> qkv [4096][3072]
    gemm_bt<false><<<dim3(24, 32), blk, 0, stream>>>(x_bf, WqkvT, bq, bk, bv, 2048, 2560,
                                                     qkv, 4096, 3072, 2048);
    // Wo -> WoT (into WqkvT's space, now dead)
    tr_f2b<<<dim3(64, 64), blk, 0, stream>>>(Wo, WoT, 2048, 2048);
    // per-batch V transpose with key permutation: qkv[b][s][2560..] -> vt[b][512][S]
    tr_vperm<<<dim3(16, 64, 2), blk, 0, stream>>>(qkv + 2560, vt_buf, 2048, 512, 3072,
                                                  (size_t)2048 * 3072, (size_t)512 * 2048);
    // attention (writes a_buf = x_bf)
    attn_kernel<<<dim3(16, 32, 2), blk, 0, stream>>>(qkv, vt_buf, mask, a_buf);
    // output projection (f32 out)
    gemm_bt<true><<<dim3(16, 32), blk, 0, stream>>>(a_buf, WoT, bo, bo, bo, BIG, BIG,
                                                    out, 4096, 2048, 2048);
}

// Round 8
// 346.941 us; speedup vs baseline: 1.0251x; 1.0019x over previous
//
#include <hip/hip_runtime.h>

typedef __attribute__((ext_vector_type(8))) short short8;
typedef __attribute__((ext_vector_type(4))) float floatx4;
typedef __attribute__((ext_vector_type(4))) unsigned int uintx4;

#define B_ 2
#define S_ 2048
#define H_ 2048
#define LOG2E 1.44269504088896f

#define MFMA(a, b, c) __builtin_amdgcn_mfma_f32_16x16x32_bf16(a, b, c, 0, 0, 0)

__device__ __forceinline__ unsigned short f2bf(float f) {
    unsigned int x = __builtin_bit_cast(unsigned int, f);
    unsigned int r = x + 0x7FFFu + ((x >> 16) & 1u);
    return (unsigned short)(r >> 16);
}

__device__ __forceinline__ void gload_lds16(const unsigned short* g, unsigned short* l) {
    __builtin_amdgcn_global_load_lds(
        (const __attribute__((address_space(1))) void*)g,
        (__attribute__((address_space(3))) void*)l, 16, 0, 0);
}

// ---------------- elementwise f32 -> bf16 convert (vectorized) ---------------
__global__ __launch_bounds__(256) void conv_f2b(const float* __restrict__ in,
                                                unsigned short* __restrict__ out, int n4) {
    int i = blockIdx.x * 256 + threadIdx.x;
    if (i < n4) {
        float4 v = ((const float4*)in)[i];
        ushort4 o;
        o.x = f2bf(v.x); o.y = f2bf(v.y); o.z = f2bf(v.z); o.w = f2bf(v.w);
        ((ushort4*)out)[i] = o;
    }
}

// ---------------- tiled transpose+convert: f32 in[R][C] -> bf16 out[C][R] ----
__global__ __launch_bounds__(256) void tr_f2b(const float* __restrict__ in,
                                              unsigned short* __restrict__ out,
                                              int R, int C) {
    __shared__ unsigned short t[32][33];
    int c0 = blockIdx.x * 32, r0 = blockIdx.y * 32;
    int tx = threadIdx.x & 31, ty = threadIdx.x >> 5;  // 32 x 8
#pragma unroll
    for (int i = 0; i < 32; i += 8)
        t[ty + i][tx] = f2bf(in[(size_t)(r0 + ty + i) * C + c0 + tx]);
    __syncthreads();
#pragma unroll
    for (int i = 0; i < 32; i += 8)
        out[(size_t)(c0 + ty + i) * R + r0 + tx] = t[tx][ty + i];
}

// -------- fused Wq/Wk/Wv transpose+convert into WqkvT[3072][2048] ------------
__global__ __launch_bounds__(256) void tr_wqkv(const float* __restrict__ Wq,
                                               const float* __restrict__ Wk,
                                               const float* __restrict__ Wv,
                                               unsigned short* __restrict__ WqkvT) {
    __shared__ unsigned short t[32][33];
    int bx = blockIdx.x;  // 0..95
    const float* src; int C, c0, orow;
    if (bx < 64)      { src = Wq; C = 2048; c0 = bx * 32;        orow = bx * 32; }
    else if (bx < 80) { src = Wk; C = 512;  c0 = (bx - 64) * 32; orow = 2048 + (bx - 64) * 32; }
    else              { src = Wv; C = 512;  c0 = (bx - 80) * 32; orow = 2560 + (bx - 80) * 32; }
    int r0 = blockIdx.y * 32;
    int tx = threadIdx.x & 31, ty = threadIdx.x >> 5;
#pragma unroll
    for (int i = 0; i < 32; i += 8)
        t[ty + i][tx] = f2bf(src[(size_t)(r0 + ty + i) * C + c0 + tx]);
    __syncthreads();
#pragma unroll
    for (int i = 0; i < 32; i += 8)
        WqkvT[(size_t)(orow + ty + i) * 2048 + r0 + tx] = t[tx][ty + i];
}

// -------- bf16 V transpose with key-permuted output columns ------------------
// out[channel][s'] where within each 64-key block, key s = 16j+4q+i is stored
// at column s' = 32*(j>>1) + 8q + 4*(j&1) + i. Inverse: stored col p holds key
// 16*(2*(p>>5) + ((p>>2)&1)) + 4*((p>>3)&3) + (p&3). With the attn PV B-frag
// reading stored cols kk*32+quad*8+e, slot (kk,quad,e) holds key
// 16*(2kk+(e>>2)) + 4*quad + (e&3) -- exactly the keys the swapped-QK^T
// fragment leaves lane-local, so the P A-fragment is a pure register
// rearrangement. Bijective within each 64-block; full 64B-line coverage.
__global__ __launch_bounds__(256) void tr_vperm(const unsigned short* __restrict__ in,
                                                unsigned short* __restrict__ out,
                                                int R, int C, int ipitch,
                                                size_t ibs, size_t obs) {
    __shared__ unsigned short t[32][33];
    in += (size_t)blockIdx.z * ibs; out += (size_t)blockIdx.z * obs;
    int c0 = blockIdx.x * 32, r0 = blockIdx.y * 32;
    int tx = threadIdx.x & 31, ty = threadIdx.x >> 5;
#pragma unroll
    for (int i = 0; i < 32; i += 8)
        t[ty + i][tx] = in[(size_t)(r0 + ty + i) * ipitch + c0 + tx];
    __syncthreads();
    int s = r0 + tx;
    int sl = s & 63;
    int j = sl >> 4, q = (sl >> 2) & 3, ii = sl & 3;
    int sp = (s & ~63) + ((j >> 1) << 5) + (q << 3) + ((j & 1) << 2) + ii;
#pragma unroll
    for (int i = 0; i < 32; i += 8)
        out[(size_t)(c0 + ty + i) * R + sp] = t[tx][ty + i];
}

// ---------------- GEMM: C[M][N] = A[M][K] x Bt[N][K]^T + bias ----------------
// bias from 3 arrays split at columns s1/s2 (pass s1=s2=1<<30 for single bias).
template <bool OUT_F32>
__global__ __launch_bounds__(256) void gemm_bt(const unsigned short* __restrict__ A,
                                               const unsigned short* __restrict__ Bt,
                                               const float* __restrict__ b0,
                                               const float* __restrict__ b1,
                                               const float* __restrict__ b2,
                                               int s1, int s2,
                                               void* __restrict__ Cv,
                                               int M, int N, int K) {
    __shared__ unsigned short As[128 * 64];
    __shared__ unsigned short Bs[128 * 64];
    const int t = threadIdx.x;
    const int lane = t & 63;
    const int wave = t >> 6;
    const int qlane = lane & 15;
    const int quad = lane >> 4;
    const int wm = (wave >> 1) * 64;
    const int wn = (wave & 1) * 64;
    const int bm = blockIdx.y * 128;
    const int bn = blockIdx.x * 128;
    const int srow = t >> 3;
    const int scc = (t & 7) * 8;
    const int gc8 = (((t & 7) ^ (2 * ((t >> 5) & 3))) * 8);
    const int rsw = 2 * (qlane >> 2);

    floatx4 acc[4][4] = {};

    for (int k0 = 0; k0 < K; k0 += 64) {
        __syncthreads();
#pragma unroll
        for (int r = 0; r < 4; ++r) {
            int row = r * 32 + srow;
            gload_lds16(A + (size_t)(bm + row) * K + k0 + gc8, &As[row * 64 + scc]);
        }
#pragma unroll
        for (int r = 0; r < 4; ++r) {
            int row = r * 32 + srow;
            gload_lds16(Bt + (size_t)(bn + row) * K + k0 + gc8, &Bs[row * 64 + scc]);
        }
        __syncthreads();
#pragma unroll
        for (int kk = 0; kk < 2; ++kk) {
            short8 a[4], b[4];
#pragma unroll
            for (int i = 0; i < 4; ++i)
                a[i] = *(const short8*)&As[(wm + i * 16 + qlane) * 64 + ((kk * 4 + quad) ^ rsw) * 8];
#pragma unroll
            for (int j = 0; j < 4; ++j)
                b[j] = *(const short8*)&Bs[(wn + j * 16 + qlane) * 64 + ((kk * 4 + quad) ^ rsw) * 8];
#pragma unroll
            for (int i = 0; i < 4; ++i)
#pragma unroll
                for (int j = 0; j < 4; ++j)
                    acc[i][j] = MFMA(a[i], b[j], acc[i][j]);
        }
    }
#pragma unroll
    for (int j = 0; j < 4; ++j) {
        int col = bn + wn + j * 16 + qlane;
        int cc = col; const float* bp = b0;
        if (col >= s2)      { bp = b2; cc = col - s2; }
        else if (col >= s1) { bp = b1; cc = col - s1; }
        float bvv = bp[cc];
#pragma unroll
        for (int i = 0; i < 4; ++i) {
            int row0 = bm + wm + i * 16 + quad * 4;
#pragma unroll
            for (int r = 0; r < 4; ++r) {
                float v = acc[i][j][r] + bvv;
                if (OUT_F32)
                    ((float*)Cv)[(size_t)(row0 + r) * N + col] = v;
                else
                    ((unsigned short*)Cv)[(size_t)(row0 + r) * N + col] = f2bf(v);
            }
        }
    }
}

// ---------------- Flash attention (128-row Q tiles, 32 rows/wave) ------------
// grid (16 qtiles, 32 heads, 2 batch) = 1024 blocks, 256 threads.
// LDS = 24KB (Ks single 8K + Vts dbuf 16K) -> 4 blocks/CU (grid-capped),
// all 1024 blocks co-resident, zero dispatch tail.
// STAGING: R5/R6-proven two-barrier schedule (V(kt+1) issued at top, drains
// at barrier A; K(kt+1) issued after A, drains at barrier B).
// COMPUTE: R6-proven swapped QK^T + register-P + key-permuted V (tr_vperm).
// ROUND 7/8 SINGLE CHANGE vs R6: pack P pairs with v_cvt_pk_bf16_f32 (guide
// T12 recipe: src1 -> lo half, src2 -> hi half; RNE rounding) instead of the
// manual half-up shift/or -- removes ~80 VALU ops/lane/kt (VALUBusy was 56%,
// the tallest pole). Numerics delta: tie-rounding only (<=1 ulp bf16).
// DIAGNOSTIC: if this fails ~3e-2, cvt_pk is the R2/R3 culprit (guide
// erratum); if it passes, R2/R3's bug was the single-barrier staging race.
__global__ __launch_bounds__(256, 4) void attn_kernel(const unsigned short* __restrict__ qkv,
                                                      const unsigned short* __restrict__ vtb,
                                                      const float* __restrict__ mask,
                                                      unsigned short* __restrict__ ob) {
    const int qt = blockIdx.x;
    const int head = blockIdx.y;
    const int b = blockIdx.z;
    const int kvh = head >> 2;
    const int qcol = head * 64;
    const int kcol = 2048 + kvh * 64;   // K slice inside qkv row
    const int vch = kvh * 64;           // Vt channel base
    const int q0 = qt * 128;
    const int t = threadIdx.x;
    const int lane = t & 63;
    const int wave = t >> 6;
    const int qlane = lane & 15;
    const int quad = lane >> 4;
    const int wr = wave * 32;

    __shared__ unsigned short Ks[64 * 64];      //  8 KB (single)
    __shared__ unsigned short Vts[2][64 * 64];  // 16 KB (double buffer)

    const int gc8 = (((t & 7) ^ (2 * ((t >> 5) & 3))) * 8);  // swizzled global chunk
    const int rsw = 2 * (qlane >> 2);                        // read-side swizzle
    const float scale2 = 0.125f * LOG2E;

    const unsigned short* vbase = vtb + (size_t)(b * 512 + vch) * S_;
    const float* mbase = mask + (size_t)b * S_;

    // Q fragments straight from global (16B contiguous per lane).
    // B-operand of swapped QK^T: col = q-row (qlane), k = d.
    short8 aq[2][2];
#pragma unroll
    for (int mi = 0; mi < 2; ++mi)
#pragma unroll
        for (int kk = 0; kk < 2; ++kk)
            aq[mi][kk] = *(const short8*)(qkv +
                (size_t)(b * S_ + q0 + wr + mi * 16 + qlane) * 3072 + qcol + kk * 32 + quad * 8);

    // prologue: stage K(0) into Ks and V(0) into Vts[0]
    {
        int row = t >> 3;
#pragma unroll
        for (int i = 0; i < 2; ++i) {
            int rr = row + 32 * i;
            gload_lds16(qkv + (size_t)(b * S_ + rr) * 3072 + kcol + gc8,
                        &Ks[(rr * 8 + (t & 7)) * 8]);
            gload_lds16(vbase + (size_t)rr * S_ + gc8,
                        &Vts[0][(rr * 8 + (t & 7)) * 8]);
        }
    }

    // ones B-fragment: B[k][0]=1 -> row-sum lands in column 0 of osum
    short8 ones;
    {
        short v = (qlane == 0) ? (short)0x3F80 : (short)0;
        ones = (short8){v, v, v, v, v, v, v, v};
    }

    floatx4 o[2][4] = {};
    floatx4 osum[2] = {};

    __syncthreads();

    for (int kt = 0; kt < 32; ++kt) {
        const int cur = kt & 1;

        // ---- (1) issue V(kt+1) into Vts[^1] (async; drains at barrier A) ----
        if (kt < 31) {
            const int nxt = cur ^ 1;
            int kn = (kt + 1) * 64;
            int row = t >> 3;
#pragma unroll
            for (int i = 0; i < 2; ++i) {
                int rr = row + 32 * i;
                gload_lds16(vbase + (size_t)rr * S_ + kn + gc8,
                            &Vts[nxt][(rr * 8 + (t & 7)) * 8]);
            }
        }

        // ---- (2) swapped QK^T + exp2 + cvt_pk pack, j-pairs ----
        // st[dj][mi][r] = S[key=16(jj+dj)+4quad+r][q=wr+mi*16+qlane]
        unsigned int pk[2][4][2];
#pragma unroll
        for (int jj = 0; jj < 4; jj += 2) {
            floatx4 st[2][2] = {};
            __builtin_amdgcn_s_setprio(1);
#pragma unroll
            for (int dj = 0; dj < 2; ++dj) {
                int j = jj + dj;
                short8 bk0 = *(const short8*)&Ks[(j * 16 + qlane) * 64 + ((0 + quad) ^ rsw) * 8];
                short8 bk1 = *(const short8*)&Ks[(j * 16 + qlane) * 64 + ((4 + quad) ^ rsw) * 8];
#pragma unroll
                for (int mi = 0; mi < 2; ++mi) {
                    st[dj][mi] = MFMA(bk0, aq[mi][0], st[dj][mi]);
                    st[dj][mi] = MFMA(bk1, aq[mi][1], st[dj][mi]);
                }
            }
            __builtin_amdgcn_s_setprio(0);
#pragma unroll
            for (int dj = 0; dj < 2; ++dj) {
                int j = jj + dj;
                floatx4 mv = *(const floatx4*)(mbase + kt * 64 + j * 16 + quad * 4);
#pragma unroll
                for (int mi = 0; mi < 2; ++mi)
#pragma unroll
                    for (int h = 0; h < 2; ++h) {
                        float p0 = __builtin_amdgcn_exp2f(st[dj][mi][2 * h]     * scale2 + mv[2 * h]     * LOG2E);
                        float p1 = __builtin_amdgcn_exp2f(st[dj][mi][2 * h + 1] * scale2 + mv[2 * h + 1] * LOG2E);
                        unsigned int r;
                        asm("v_cvt_pk_bf16_f32 %0, %1, %2" : "=v"(r) : "v"(p0), "v"(p1));
                        pk[mi][j][h] = r;  // lo = key 2h, hi = key 2h+1
                    }
            }
        }

        // ---- barrier A: all waves done reading Ks(kt); V(kt+1) landed ----
        __syncthreads();

        // ---- (3) issue K(kt+1) into Ks (async; drains at barrier B) ----
        if (kt < 31) {
            int kn = (kt + 1) * 64;
            int row = t >> 3;
#pragma unroll
            for (int i = 0; i < 2; ++i) {
                int rr = row + 32 * i;
                gload_lds16(qkv + (size_t)(b * S_ + kn + rr) * 3072 + kcol + gc8,
                            &Ks[(rr * 8 + (t & 7)) * 8]);
            }
        }

        // ---- (4) PV + row-sum: P from registers, V from Vts[cur] ----
        __builtin_amdgcn_s_setprio(1);
#pragma unroll
        for (int kk = 0; kk < 2; ++kk) {
            short8 ap[2];
#pragma unroll
            for (int mi = 0; mi < 2; ++mi) {
                uintx4 u = {pk[mi][2 * kk][0], pk[mi][2 * kk][1],
                            pk[mi][2 * kk + 1][0], pk[mi][2 * kk + 1][1]};
                ap[mi] = __builtin_bit_cast(short8, u);
            }
#pragma unroll
            for (int j2 = 0; j2 < 4; ++j2) {
                short8 bv = *(const short8*)&Vts[cur][(j2 * 16 + qlane) * 64 + ((kk * 4 + quad) ^ rsw) * 8];
#pragma unroll
                for (int mi = 0; mi < 2; ++mi)
                    o[mi][j2] = MFMA(ap[mi], bv, o[mi][j2]);
            }
#pragma unroll
            for (int mi = 0; mi < 2; ++mi)
                osum[mi] = MFMA(ap[mi], ones, osum[mi]);
        }
        __builtin_amdgcn_s_setprio(0);

        // ---- barrier B: K(kt+1) landed; Vts[cur] reads complete ----
        __syncthreads();
    }

    // ---- epilogue: broadcast row-sum (col 0 of osum), normalize, store ----
#pragma unroll
    for (int mi = 0; mi < 2; ++mi)
#pragma unroll
        for (int r = 0; r < 4; ++r) {
            float sm = __shfl(osum[mi][r], quad * 16, 64);
            float inv = 1.0f / sm;
            int row = q0 + wr + mi * 16 + quad * 4 + r;
#pragma unroll
            for (int j2 = 0; j2 < 4; ++j2)
                ob[(size_t)(b * S_ + row) * H_ + qcol + j2 * 16 + qlane] = f2bf(o[mi][j2][r] * inv);
        }
}

extern "C" void kernel_launch(void* const* d_in, const int* in_sizes, int n_in,
                              void* d_out, int out_size, void* d_ws, size_t ws_size,
                              hipStream_t stream) {
    const float* x    = (const float*)d_in[0];
    const float* mask = (const float*)d_in[1];
    const float* Wq   = (const float*)d_in[2];
    const float* bq   = (const float*)d_in[3];
    const float* Wk   = (const float*)d_in[4];
    const float* bk   = (const float*)d_in[5];
    const float* Wv   = (const float*)d_in[6];
    const float* bv   = (const float*)d_in[7];
    const float* Wo   = (const float*)d_in[8];
    const float* bo   = (const float*)d_in[9];
    float* out = (float*)d_out;

    // workspace (bf16 elems), 56 MB total:
    //   x_bf [4096][2048] (later: attn out), qkv [4096][3072],
    //   vt [2][512][2048] (key-permuted within 64-blocks),
    //   WqkvT [3072][2048] (later: WoT [2048][2048])
    unsigned short* ws = (unsigned short*)d_ws;
    unsigned short* x_bf   = ws;
    unsigned short* qkv    = x_bf + (size_t)4096 * 2048;
    unsigned short* vt_buf = qkv + (size_t)4096 * 3072;
    unsigned short* WqkvT  = vt_buf + (size_t)2 * 512 * 2048;
    unsigned short* WoT    = WqkvT;           // aliased: Wo transposed after QKV GEMM
    unsigned short* a_buf  = x_bf;            // aliased: x consumed by QKV GEMM

    const int BIG = 1 << 30;
    dim3 blk(256);
    // x -> bf16
    conv_f2b<<<dim3(4096 * 2048 / 4 / 256), blk, 0, stream>>>(x, x_bf, 4096 * 2048 / 4);
    // Wq|Wk|Wv -> WqkvT [3072][2048] (one launch)
    tr_wqkv<<<dim3(96, 64), blk, 0, stream>>>(Wq, Wk, Wv, WqkvT);
    // fused QKV projection: [4096][2048] x [3072][2048]^T -> qkv [4096][3072]
    gemm_bt<false><<<dim3(24, 32), blk, 0, stream>>>(x_bf, WqkvT, bq, bk, bv, 2048, 2560,
                                                     qkv, 4096, 3072, 2048);
    // Wo -> WoT (into WqkvT's space, now dead)
    tr_f2b<<<dim3(64, 64), blk, 0, stream>>>(Wo, WoT, 2048, 2048);
    // per-batch V transpose with key permutation: qkv[b][s][2560..] -> vt[b][512][S]
    tr_vperm<<<dim3(16, 64, 2), blk, 0, stream>>>(qkv + 2560, vt_buf, 2048, 512, 3072,
                                                  (size_t)2048 * 3072, (size_t)512 * 2048);
    // attention (writes a_buf = x_bf)
    attn_kernel<<<dim3(16, 32, 2), blk, 0, stream>>>(qkv, vt_buf, mask, a_buf);
    // output projection (f32 out)
    gemm_bt<true><<<dim3(16, 32), blk, 0, stream>>>(a_buf, WoT, bo, bo, bo, BIG, BIG,
                                                    out, 4096, 2048, 2048);
}

// Round 10
// 345.955 us; speedup vs baseline: 1.0281x; 1.0028x over previous
//
#include <hip/hip_runtime.h>

typedef __attribute__((ext_vector_type(8))) short short8;
typedef __attribute__((ext_vector_type(4))) float floatx4;
typedef __attribute__((ext_vector_type(4))) unsigned int uintx4;

#define B_ 2
#define S_ 2048
#define H_ 2048
#define LOG2E 1.44269504088896f

#define MFMA(a, b, c) __builtin_amdgcn_mfma_f32_16x16x32_bf16(a, b, c, 0, 0, 0)

__device__ __forceinline__ unsigned short f2bf(float f) {
    unsigned int x = __builtin_bit_cast(unsigned int, f);
    unsigned int r = x + 0x7FFFu + ((x >> 16) & 1u);
    return (unsigned short)(r >> 16);
}

__device__ __forceinline__ void gload_lds16(const unsigned short* g, unsigned short* l) {
    __builtin_amdgcn_global_load_lds(
        (const __attribute__((address_space(1))) void*)g,
        (__attribute__((address_space(3))) void*)l, 16, 0, 0);
}

// ------- elementwise f32 -> bf16 convert (vectorized) + mask pre-scale -------
// Last block (i >= n4) pre-scales the attention mask by LOG2E into mw --
// hoists 16 v_mul/lane/kt out of the attention hot loop (mask is loop-
// invariant per key). mw lives in the tail of d_out, dead until the final
// GEMM (which runs after attn and overwrites all of out).
__global__ __launch_bounds__(256) void conv_f2b(const float* __restrict__ in,
                                                unsigned short* __restrict__ out, int n4,
                                                const float* __restrict__ mask,
                                                float* __restrict__ mw) {
    int i = blockIdx.x * 256 + threadIdx.x;
    if (i < n4) {
        float4 v = ((const float4*)in)[i];
        ushort4 o;
        o.x = f2bf(v.x); o.y = f2bf(v.y); o.z = f2bf(v.z); o.w = f2bf(v.w);
        ((ushort4*)out)[i] = o;
    } else {
        for (int m = threadIdx.x; m < B_ * S_; m += 256)
            mw[m] = mask[m] * LOG2E;
    }
}

// ---------------- tiled transpose+convert: f32 in[R][C] -> bf16 out[C][R] ----
__global__ __launch_bounds__(256) void tr_f2b(const float* __restrict__ in,
                                              unsigned short* __restrict__ out,
                                              int R, int C) {
    __shared__ unsigned short t[32][33];
    int c0 = blockIdx.x * 32, r0 = blockIdx.y * 32;
    int tx = threadIdx.x & 31, ty = threadIdx.x >> 5;  // 32 x 8
#pragma unroll
    for (int i = 0; i < 32; i += 8)
        t[ty + i][tx] = f2bf(in[(size_t)(r0 + ty + i) * C + c0 + tx]);
    __syncthreads();
#pragma unroll
    for (int i = 0; i < 32; i += 8)
        out[(size_t)(c0 + ty + i) * R + r0 + tx] = t[tx][ty + i];
}

// -------- fused Wq/Wk/Wv transpose+convert into WqkvT[3072][2048] ------------
__global__ __launch_bounds__(256) void tr_wqkv(const float* __restrict__ Wq,
                                               const float* __restrict__ Wk,
                                               const float* __restrict__ Wv,
                                               unsigned short* __restrict__ WqkvT) {
    __shared__ unsigned short t[32][33];
    int bx = blockIdx.x;  // 0..95
    const float* src; int C, c0, orow;
    if (bx < 64)      { src = Wq; C = 2048; c0 = bx * 32;        orow = bx * 32; }
    else if (bx < 80) { src = Wk; C = 512;  c0 = (bx - 64) * 32; orow = 2048 + (bx - 64) * 32; }
    else              { src = Wv; C = 512;  c0 = (bx - 80) * 32; orow = 2560 + (bx - 80) * 32; }
    int r0 = blockIdx.y * 32;
    int tx = threadIdx.x & 31, ty = threadIdx.x >> 5;
#pragma unroll
    for (int i = 0; i < 32; i += 8)
        t[ty + i][tx] = f2bf(src[(size_t)(r0 + ty + i) * C + c0 + tx]);
    __syncthreads();
#pragma unroll
    for (int i = 0; i < 32; i += 8)
        WqkvT[(size_t)(orow + ty + i) * 2048 + r0 + tx] = t[tx][ty + i];
}

// -------- bf16 V transpose with key-permuted output columns ------------------
// out[channel][s'] where within each 64-key block, key s = 16j+4q+i is stored
// at column s' = 32*(j>>1) + 8q + 4*(j&1) + i. Inverse: stored col p holds key
// 16*(2*(p>>5) + ((p>>2)&1)) + 4*((p>>3)&3) + (p&3). With the attn PV B-frag
// reading stored cols kk*32+quad*8+e, slot (kk,quad,e) holds key
// 16*(2kk+(e>>2)) + 4*quad + (e&3) -- exactly the keys the swapped-QK^T
// fragment leaves lane-local, so the P A-fragment is a pure register
// rearrangement. Bijective within each 64-block; full 64B-line coverage.
__global__ __launch_bounds__(256) void tr_vperm(const unsigned short* __restrict__ in,
                                                unsigned short* __restrict__ out,
                                                int R, int C, int ipitch,
                                                size_t ibs, size_t obs) {
    __shared__ unsigned short t[32][33];
    in += (size_t)blockIdx.z * ibs; out += (size_t)blockIdx.z * obs;
    int c0 = blockIdx.x * 32, r0 = blockIdx.y * 32;
    int tx = threadIdx.x & 31, ty = threadIdx.x >> 5;
#pragma unroll
    for (int i = 0; i < 32; i += 8)
        t[ty + i][tx] = in[(size_t)(r0 + ty + i) * ipitch + c0 + tx];
    __syncthreads();
    int s = r0 + tx;
    int sl = s & 63;
    int j = sl >> 4, q = (sl >> 2) & 3, ii = sl & 3;
    int sp = (s & ~63) + ((j >> 1) << 5) + (q << 3) + ((j & 1) << 2) + ii;
#pragma unroll
    for (int i = 0; i < 32; i += 8)
        out[(size_t)(c0 + ty + i) * R + sp] = t[tx][ty + i];
}

// ---------------- GEMM: C[M][N] = A[M][K] x Bt[N][K]^T + bias ----------------
// bias from 3 arrays split at columns s1/s2 (pass s1=s2=1<<30 for single bias).
template <bool OUT_F32>
__global__ __launch_bounds__(256) void gemm_bt(const unsigned short* __restrict__ A,
                                               const unsigned short* __restrict__ Bt,
                                               const float* __restrict__ b0,
                                               const float* __restrict__ b1,
                                               const float* __restrict__ b2,
                                               int s1, int s2,
                                               void* __restrict__ Cv,
                                               int M, int N, int K) {
    __shared__ unsigned short As[128 * 64];
    __shared__ unsigned short Bs[128 * 64];
    const int t = threadIdx.x;
    const int lane = t & 63;
    const int wave = t >> 6;
    const int qlane = lane & 15;
    const int quad = lane >> 4;
    const int wm = (wave >> 1) * 64;
    const int wn = (wave & 1) * 64;
    const int bm = blockIdx.y * 128;
    const int bn = blockIdx.x * 128;
    const int srow = t >> 3;
    const int scc = (t & 7) * 8;
    const int gc8 = (((t & 7) ^ (2 * ((t >> 5) & 3))) * 8);
    const int rsw = 2 * (qlane >> 2);

    floatx4 acc[4][4] = {};

    for (int k0 = 0; k0 < K; k0 += 64) {
        __syncthreads();
#pragma unroll
        for (int r = 0; r < 4; ++r) {
            int row = r * 32 + srow;
            gload_lds16(A + (size_t)(bm + row) * K + k0 + gc8, &As[row * 64 + scc]);
        }
#pragma unroll
        for (int r = 0; r < 4; ++r) {
            int row = r * 32 + srow;
            gload_lds16(Bt + (size_t)(bn + row) * K + k0 + gc8, &Bs[row * 64 + scc]);
        }
        __syncthreads();
#pragma unroll
        for (int kk = 0; kk < 2; ++kk) {
            short8 a[4], b[4];
#pragma unroll
            for (int i = 0; i < 4; ++i)
                a[i] = *(const short8*)&As[(wm + i * 16 + qlane) * 64 + ((kk * 4 + quad) ^ rsw) * 8];
#pragma unroll
            for (int j = 0; j < 4; ++j)
                b[j] = *(const short8*)&Bs[(wn + j * 16 + qlane) * 64 + ((kk * 4 + quad) ^ rsw) * 8];
#pragma unroll
            for (int i = 0; i < 4; ++i)
#pragma unroll
                for (int j = 0; j < 4; ++j)
                    acc[i][j] = MFMA(a[i], b[j], acc[i][j]);
        }
    }
#pragma unroll
    for (int j = 0; j < 4; ++j) {
        int col = bn + wn + j * 16 + qlane;
        int cc = col; const float* bp = b0;
        if (col >= s2)      { bp = b2; cc = col - s2; }
        else if (col >= s1) { bp = b1; cc = col - s1; }
        float bvv = bp[cc];
#pragma unroll
        for (int i = 0; i < 4; ++i) {
            int row0 = bm + wm + i * 16 + quad * 4;
#pragma unroll
            for (int r = 0; r < 4; ++r) {
                float v = acc[i][j][r] + bvv;
                if (OUT_F32)
                    ((float*)Cv)[(size_t)(row0 + r) * N + col] = v;
                else
                    ((unsigned short*)Cv)[(size_t)(row0 + r) * N + col] = f2bf(v);
            }
        }
    }
}

// ---------------- Flash attention (128-row Q tiles, 32 rows/wave) ------------
// grid (16 qtiles, 32 heads, 2 batch) = 1024 blocks, 256 threads.
// LDS = 24KB (Ks single 8K + Vts dbuf 16K) -> 4 blocks/CU (grid-capped),
// all 1024 blocks co-resident, zero dispatch tail.
// STAGING: R5/R6/R8-proven two-barrier schedule (V(kt+1) issued at top,
// drains at barrier A; K(kt+1) issued after A, drains at barrier B).
// NOTE: single-barrier dbuf (R2/R3) empirically FAILS numerically on this
// structure -- do not regress to it.
// COMPUTE: R8-proven swapped QK^T + register-P (cvt_pk pack, T12 recipe
// verified on HW here in R8) + key-permuted V (tr_vperm).
// ROUND 10 (= R9 resubmit) SINGLE CHANGE: mask arrives pre-scaled by LOG2E
// (mw, computed in conv_f2b's extra block) -- drops 16 v_mul/lane/kt from
// the hot loop (VALUBusy was 51%, the tallest pole). Bit-identical output.
__global__ __launch_bounds__(256, 4) void attn_kernel(const unsigned short* __restrict__ qkv,
                                                      const unsigned short* __restrict__ vtb,
                                                      const float* __restrict__ mw,
                                                      unsigned short* __restrict__ ob) {
    const int qt = blockIdx.x;
    const int head = blockIdx.y;
    const int b = blockIdx.z;
    const int kvh = head >> 2;
    const int qcol = head * 64;
    const int kcol = 2048 + kvh * 64;   // K slice inside qkv row
    const int vch = kvh * 64;           // Vt channel base
    const int q0 = qt * 128;
    const int t = threadIdx.x;
    const int lane = t & 63;
    const int wave = t >> 6;
    const int qlane = lane & 15;
    const int quad = lane >> 4;
    const int wr = wave * 32;

    __shared__ unsigned short Ks[64 * 64];      //  8 KB (single)
    __shared__ unsigned short Vts[2][64 * 64];  // 16 KB (double buffer)

    const int gc8 = (((t & 7) ^ (2 * ((t >> 5) & 3))) * 8);  // swizzled global chunk
    const int rsw = 2 * (qlane >> 2);                        // read-side swizzle
    const float scale2 = 0.125f * LOG2E;

    const unsigned short* vbase = vtb + (size_t)(b * 512 + vch) * S_;
    const float* mbase = mw + (size_t)b * S_;

    // Q fragments straight from global (16B contiguous per lane).
    // B-operand of swapped QK^T: col = q-row (qlane), k = d.
    short8 aq[2][2];
#pragma unroll
    for (int mi = 0; mi < 2; ++mi)
#pragma unroll
        for (int kk = 0; kk < 2; ++kk)
            aq[mi][kk] = *(const short8*)(qkv +
                (size_t)(b * S_ + q0 + wr + mi * 16 + qlane) * 3072 + qcol + kk * 32 + quad * 8);

    // prologue: stage K(0) into Ks and V(0) into Vts[0]
    {
        int row = t >> 3;
#pragma unroll
        for (int i = 0; i < 2; ++i) {
            int rr = row + 32 * i;
            gload_lds16(qkv + (size_t)(b * S_ + rr) * 3072 + kcol + gc8,
                        &Ks[(rr * 8 + (t & 7)) * 8]);
            gload_lds16(vbase + (size_t)rr * S_ + gc8,
                        &Vts[0][(rr * 8 + (t & 7)) * 8]);
        }
    }

    // ones B-fragment: B[k][0]=1 -> row-sum lands in column 0 of osum
    short8 ones;
    {
        short v = (qlane == 0) ? (short)0x3F80 : (short)0;
        ones = (short8){v, v, v, v, v, v, v, v};
    }

    floatx4 o[2][4] = {};
    floatx4 osum[2] = {};

    __syncthreads();

    for (int kt = 0; kt < 32; ++kt) {
        const int cur = kt & 1;

        // ---- (1) issue V(kt+1) into Vts[^1] (async; drains at barrier A) ----
        if (kt < 31) {
            const int nxt = cur ^ 1;
            int kn = (kt + 1) * 64;
            int row = t >> 3;
#pragma unroll
            for (int i = 0; i < 2; ++i) {
                int rr = row + 32 * i;
                gload_lds16(vbase + (size_t)rr * S_ + kn + gc8,
                            &Vts[nxt][(rr * 8 + (t & 7)) * 8]);
            }
        }

        // ---- (2) swapped QK^T + exp2 + cvt_pk pack, j-pairs ----
        // st[dj][mi][r] = S[key=16(jj+dj)+4quad+r][q=wr+mi*16+qlane]
        unsigned int pk[2][4][2];
#pragma unroll
        for (int jj = 0; jj < 4; jj += 2) {
            floatx4 st[2][2] = {};
            __builtin_amdgcn_s_setprio(1);
#pragma unroll
            for (int dj = 0; dj < 2; ++dj) {
                int j = jj + dj;
                short8 bk0 = *(const short8*)&Ks[(j * 16 + qlane) * 64 + ((0 + quad) ^ rsw) * 8];
                short8 bk1 = *(const short8*)&Ks[(j * 16 + qlane) * 64 + ((4 + quad) ^ rsw) * 8];
#pragma unroll
                for (int mi = 0; mi < 2; ++mi) {
                    st[dj][mi] = MFMA(bk0, aq[mi][0], st[dj][mi]);
                    st[dj][mi] = MFMA(bk1, aq[mi][1], st[dj][mi]);
                }
            }
            __builtin_amdgcn_s_setprio(0);
#pragma unroll
            for (int dj = 0; dj < 2; ++dj) {
                int j = jj + dj;
                floatx4 mv = *(const floatx4*)(mbase + kt * 64 + j * 16 + quad * 4);
#pragma unroll
                for (int mi = 0; mi < 2; ++mi)
#pragma unroll
                    for (int h = 0; h < 2; ++h) {
                        float p0 = __builtin_amdgcn_exp2f(st[dj][mi][2 * h]     * scale2 + mv[2 * h]);
                        float p1 = __builtin_amdgcn_exp2f(st[dj][mi][2 * h + 1] * scale2 + mv[2 * h + 1]);
                        unsigned int r;
                        asm("v_cvt_pk_bf16_f32 %0, %1, %2" : "=v"(r) : "v"(p0), "v"(p1));
                        pk[mi][j][h] = r;  // lo = key 2h, hi = key 2h+1
                    }
            }
        }

        // ---- barrier A: all waves done reading Ks(kt); V(kt+1) landed ----
        __syncthreads();

        // ---- (3) issue K(kt+1) into Ks (async; drains at barrier B) ----
        if (kt < 31) {
            int kn = (kt + 1) * 64;
            int row = t >> 3;
#pragma unroll
            for (int i = 0; i < 2; ++i) {
                int rr = row + 32 * i;
                gload_lds16(qkv + (size_t)(b * S_ + kn + rr) * 3072 + kcol + gc8,
                            &Ks[(rr * 8 + (t & 7)) * 8]);
            }
        }

        // ---- (4) PV + row-sum: P from registers, V from Vts[cur] ----
        __builtin_amdgcn_s_setprio(1);
#pragma unroll
        for (int kk = 0; kk < 2; ++kk) {
            short8 ap[2];
#pragma unroll
            for (int mi = 0; mi < 2; ++mi) {
                uintx4 u = {pk[mi][2 * kk][0], pk[mi][2 * kk][1],
                            pk[mi][2 * kk + 1][0], pk[mi][2 * kk + 1][1]};
                ap[mi] = __builtin_bit_cast(short8, u);
            }
#pragma unroll
            for (int j2 = 0; j2 < 4; ++j2) {
                short8 bv = *(const short8*)&Vts[cur][(j2 * 16 + qlane) * 64 + ((kk * 4 + quad) ^ rsw) * 8];
#pragma unroll
                for (int mi = 0; mi < 2; ++mi)
                    o[mi][j2] = MFMA(ap[mi], bv, o[mi][j2]);
            }
#pragma unroll
            for (int mi = 0; mi < 2; ++mi)
                osum[mi] = MFMA(ap[mi], ones, osum[mi]);
        }
        __builtin_amdgcn_s_setprio(0);

        // ---- barrier B: K(kt+1) landed; Vts[cur] reads complete ----
        __syncthreads();
    }

    // ---- epilogue: broadcast row-sum (col 0 of osum), normalize, store ----
#pragma unroll
    for (int mi = 0; mi < 2; ++mi)
#pragma unroll
        for (int r = 0; r < 4; ++r) {
            float sm = __shfl(osum[mi][r], quad * 16, 64);
            float inv = 1.0f / sm;
            int row = q0 + wr + mi * 16 + quad * 4 + r;
#pragma unroll
            for (int j2 = 0; j2 < 4; ++j2)
                ob[(size_t)(b * S_ + row) * H_ + qcol + j2 * 16 + qlane] = f2bf(o[mi][j2][r] * inv);
        }
}

extern "C" void kernel_launch(void* const* d_in, const int* in_sizes, int n_in,
                              void* d_out, int out_size, void* d_ws, size_t ws_size,
                              hipStream_t stream) {
    const float* x    = (const float*)d_in[0];
    const float* mask = (const float*)d_in[1];
    const float* Wq   = (const float*)d_in[2];
    const float* bq   = (const float*)d_in[3];
    const float* Wk   = (const float*)d_in[4];
    const float* bk   = (const float*)d_in[5];
    const float* Wv   = (const float*)d_in[6];
    const float* bv   = (const float*)d_in[7];
    const float* Wo   = (const float*)d_in[8];
    const float* bo   = (const float*)d_in[9];
    float* out = (float*)d_out;

    // workspace (bf16 elems), ~59 MB total:
    //   x_bf [4096][2048] (later: attn out), qkv [4096][3072],
    //   vt [2][512][2048] (key-permuted within 64-blocks),
    //   WqkvT [3072][2048] (later: WoT [2048][2048])
    unsigned short* ws = (unsigned short*)d_ws;
    unsigned short* x_bf   = ws;
    unsigned short* qkv    = x_bf + (size_t)4096 * 2048;
    unsigned short* vt_buf = qkv + (size_t)4096 * 3072;
    unsigned short* WqkvT  = vt_buf + (size_t)2 * 512 * 2048;
    unsigned short* WoT    = WqkvT;           // aliased: Wo transposed after QKV GEMM
    unsigned short* a_buf  = x_bf;            // aliased: x consumed by QKV GEMM

    // pre-scaled mask (mask * LOG2E), parked in the TAIL of d_out: written by
    // conv_f2b, read by attn, clobbered only by the final GEMM (runs after).
    float* mw = out + (size_t)4096 * 2048 - B_ * S_;

    const int BIG = 1 << 30;
    dim3 blk(256);
    // x -> bf16 (+1 block: mask pre-scale into mw)
    conv_f2b<<<dim3(4096 * 2048 / 4 / 256 + 1), blk, 0, stream>>>(x, x_bf, 4096 * 2048 / 4,
                                                                  mask, mw);
    // Wq|Wk|Wv -> WqkvT [3072][2048] (one launch)
    tr_wqkv<<<dim3(96, 64), blk, 0, stream>>>(Wq, Wk, Wv, WqkvT);
    // fused QKV projection: [4096][2048] x [3072][2048]^T -> qkv [4096][3072]
    gemm_bt<false><<<dim3(24, 32), blk, 0, stream>>>(x_bf, WqkvT, bq, bk, bv, 2048, 2560,
                                                     qkv, 4096, 3072, 2048);
    // Wo -> WoT (into WqkvT's space, now dead)
    tr_f2b<<<dim3(64, 64), blk, 0, stream>>>(Wo, WoT, 2048, 2048);
    // per-batch V transpose with key permutation: qkv[b][s][2560..] -> vt[b][512][S]
    tr_vperm<<<dim3(16, 64, 2), blk, 0, stream>>>(qkv + 2560, vt_buf, 2048, 512, 3072,
                                                  (size_t)2048 * 3072, (size_t)512 * 2048);
    // attention (reads mw, writes a_buf = x_bf)
    attn_kernel<<<dim3(16, 32, 2), blk, 0, stream>>>(qkv, vt_buf, mw, a_buf);
    // output projection (f32 out; overwrites mw region last)
    gemm_bt<true><<<dim3(16, 32), blk, 0, stream>>>(a_buf, WoT, bo, bo, bo, BIG, BIG,
                                                    out, 4096, 2048, 2048);
}

// Round 11
// 328.622 us; speedup vs baseline: 1.0823x; 1.0527x over previous
//
#include <hip/hip_runtime.h>

typedef __attribute__((ext_vector_type(8))) short short8;
typedef __attribute__((ext_vector_type(4))) float floatx4;
typedef __attribute__((ext_vector_type(4))) unsigned int uintx4;

#define B_ 2
#define S_ 2048
#define H_ 2048
#define LOG2E 1.44269504088896f

#define MFMA(a, b, c) __builtin_amdgcn_mfma_f32_16x16x32_bf16(a, b, c, 0, 0, 0)

__device__ __forceinline__ unsigned short f2bf(float f) {
    unsigned int x = __builtin_bit_cast(unsigned int, f);
    unsigned int r = x + 0x7FFFu + ((x >> 16) & 1u);
    return (unsigned short)(r >> 16);
}

__device__ __forceinline__ void gload_lds16(const unsigned short* g, unsigned short* l) {
    __builtin_amdgcn_global_load_lds(
        (const __attribute__((address_space(1))) void*)g,
        (__attribute__((address_space(3))) void*)l, 16, 0, 0);
}

// ------- elementwise f32 -> bf16 convert (vectorized) + mask pre-scale -------
__global__ __launch_bounds__(256) void conv_f2b(const float* __restrict__ in,
                                                unsigned short* __restrict__ out, int n4,
                                                const float* __restrict__ mask,
                                                float* __restrict__ mw) {
    int i = blockIdx.x * 256 + threadIdx.x;
    if (i < n4) {
        float4 v = ((const float4*)in)[i];
        ushort4 o;
        o.x = f2bf(v.x); o.y = f2bf(v.y); o.z = f2bf(v.z); o.w = f2bf(v.w);
        ((ushort4*)out)[i] = o;
    } else {
        for (int m = threadIdx.x; m < B_ * S_; m += 256)
            mw[m] = mask[m] * LOG2E;
    }
}

// ---------------- tiled transpose+convert: f32 in[R][C] -> bf16 out[C][R] ----
__global__ __launch_bounds__(256) void tr_f2b(const float* __restrict__ in,
                                              unsigned short* __restrict__ out,
                                              int R, int C) {
    __shared__ unsigned short t[32][33];
    int c0 = blockIdx.x * 32, r0 = blockIdx.y * 32;
    int tx = threadIdx.x & 31, ty = threadIdx.x >> 5;  // 32 x 8
#pragma unroll
    for (int i = 0; i < 32; i += 8)
        t[ty + i][tx] = f2bf(in[(size_t)(r0 + ty + i) * C + c0 + tx]);
    __syncthreads();
#pragma unroll
    for (int i = 0; i < 32; i += 8)
        out[(size_t)(c0 + ty + i) * R + r0 + tx] = t[tx][ty + i];
}

// -------- fused Wq/Wk/Wv transpose+convert into WqkvT[3072][2048] ------------
__global__ __launch_bounds__(256) void tr_wqkv(const float* __restrict__ Wq,
                                               const float* __restrict__ Wk,
                                               const float* __restrict__ Wv,
                                               unsigned short* __restrict__ WqkvT) {
    __shared__ unsigned short t[32][33];
    int bx = blockIdx.x;  // 0..95
    const float* src; int C, c0, orow;
    if (bx < 64)      { src = Wq; C = 2048; c0 = bx * 32;        orow = bx * 32; }
    else if (bx < 80) { src = Wk; C = 512;  c0 = (bx - 64) * 32; orow = 2048 + (bx - 64) * 32; }
    else              { src = Wv; C = 512;  c0 = (bx - 80) * 32; orow = 2560 + (bx - 80) * 32; }
    int r0 = blockIdx.y * 32;
    int tx = threadIdx.x & 31, ty = threadIdx.x >> 5;
#pragma unroll
    for (int i = 0; i < 32; i += 8)
        t[ty + i][tx] = f2bf(src[(size_t)(r0 + ty + i) * C + c0 + tx]);
    __syncthreads();
#pragma unroll
    for (int i = 0; i < 32; i += 8)
        WqkvT[(size_t)(orow + ty + i) * 2048 + r0 + tx] = t[tx][ty + i];
}

// -------- bf16 V transpose with key-permuted output columns ------------------
__global__ __launch_bounds__(256) void tr_vperm(const unsigned short* __restrict__ in,
                                                unsigned short* __restrict__ out,
                                                int R, int C, int ipitch,
                                                size_t ibs, size_t obs) {
    __shared__ unsigned short t[32][33];
    in += (size_t)blockIdx.z * ibs; out += (size_t)blockIdx.z * obs;
    int c0 = blockIdx.x * 32, r0 = blockIdx.y * 32;
    int tx = threadIdx.x & 31, ty = threadIdx.x >> 5;
#pragma unroll
    for (int i = 0; i < 32; i += 8)
        t[ty + i][tx] = in[(size_t)(r0 + ty + i) * ipitch + c0 + tx];
    __syncthreads();
    int s = r0 + tx;
    int sl = s & 63;
    int j = sl >> 4, q = (sl >> 2) & 3, ii = sl & 3;
    int sp = (s & ~63) + ((j >> 1) << 5) + (q << 3) + ((j & 1) << 2) + ii;
#pragma unroll
    for (int i = 0; i < 32; i += 8)
        out[(size_t)(c0 + ty + i) * R + sp] = t[tx][ty + i];
}

// ---------------- GEMM: C[M][N] = A[M][K] x Bt[N][K]^T + bias ----------------
// (m97-structure 128x128 tile; kept for the output projection.)
template <bool OUT_F32>
__global__ __launch_bounds__(256) void gemm_bt(const unsigned short* __restrict__ A,
                                               const unsigned short* __restrict__ Bt,
                                               const float* __restrict__ b0,
                                               const float* __restrict__ b1,
                                               const float* __restrict__ b2,
                                               int s1, int s2,
                                               void* __restrict__ Cv,
                                               int M, int N, int K) {
    __shared__ unsigned short As[128 * 64];
    __shared__ unsigned short Bs[128 * 64];
    const int t = threadIdx.x;
    const int lane = t & 63;
    const int wave = t >> 6;
    const int qlane = lane & 15;
    const int quad = lane >> 4;
    const int wm = (wave >> 1) * 64;
    const int wn = (wave & 1) * 64;
    const int bm = blockIdx.y * 128;
    const int bn = blockIdx.x * 128;
    const int srow = t >> 3;
    const int scc = (t & 7) * 8;
    const int gc8 = (((t & 7) ^ (2 * ((t >> 5) & 3))) * 8);
    const int rsw = 2 * (qlane >> 2);

    floatx4 acc[4][4] = {};

    for (int k0 = 0; k0 < K; k0 += 64) {
        __syncthreads();
#pragma unroll
        for (int r = 0; r < 4; ++r) {
            int row = r * 32 + srow;
            gload_lds16(A + (size_t)(bm + row) * K + k0 + gc8, &As[row * 64 + scc]);
        }
#pragma unroll
        for (int r = 0; r < 4; ++r) {
            int row = r * 32 + srow;
            gload_lds16(Bt + (size_t)(bn + row) * K + k0 + gc8, &Bs[row * 64 + scc]);
        }
        __syncthreads();
#pragma unroll
        for (int kk = 0; kk < 2; ++kk) {
            short8 a[4], b[4];
#pragma unroll
            for (int i = 0; i < 4; ++i)
                a[i] = *(const short8*)&As[(wm + i * 16 + qlane) * 64 + ((kk * 4 + quad) ^ rsw) * 8];
#pragma unroll
            for (int j = 0; j < 4; ++j)
                b[j] = *(const short8*)&Bs[(wn + j * 16 + qlane) * 64 + ((kk * 4 + quad) ^ rsw) * 8];
#pragma unroll
            for (int i = 0; i < 4; ++i)
#pragma unroll
                for (int j = 0; j < 4; ++j)
                    acc[i][j] = MFMA(a[i], b[j], acc[i][j]);
        }
    }
#pragma unroll
    for (int j = 0; j < 4; ++j) {
        int col = bn + wn + j * 16 + qlane;
        int cc = col; const float* bp = b0;
        if (col >= s2)      { bp = b2; cc = col - s2; }
        else if (col >= s1) { bp = b1; cc = col - s1; }
        float bvv = bp[cc];
#pragma unroll
        for (int i = 0; i < 4; ++i) {
            int row0 = bm + wm + i * 16 + quad * 4;
#pragma unroll
            for (int r = 0; r < 4; ++r) {
                float v = acc[i][j][r] + bvv;
                if (OUT_F32)
                    ((float*)Cv)[(size_t)(row0 + r) * N + col] = v;
                else
                    ((unsigned short*)Cv)[(size_t)(row0 + r) * N + col] = f2bf(v);
            }
        }
    }
}

// ------- stage one 128-row half-tile (128 x 64 bf16) via global_load_lds -----
// Same gc8/scc swizzle pair as gemm_bt (proven): LDS[row][c] holds global
// chunk c ^ 2*((row>>2)&3); read side applies ^rsw to invert. Dest address is
// linear in t (wave-uniform base + lane*16) as gload_lds requires.
__device__ __forceinline__ void stage_half(const unsigned short* __restrict__ gsrc,
                                           unsigned short* __restrict__ ldst,
                                           int t, int K) {
    const int srow = t >> 3;                                  // 0..63
    const int scc = (t & 7) * 8;
    const int gc8 = (((t & 7) ^ (2 * ((t >> 5) & 3))) * 8);
#pragma unroll
    for (int r = 0; r < 2; ++r) {
        int row = r * 64 + srow;                              // 0..127
        gload_lds16(gsrc + (size_t)row * K + gc8, &ldst[row * 64 + scc]);
    }
}

// -------- 256x256-tile GEMM, 8 waves, BK=64, 4-phase pipelined K-loop --------
// Port of the guide's 8-phase template (T3+T5; plain HIP). LDS 128KB: A,B
// double-buffered [2][256][64]. Per K-tile i (buf c=i&1): 4 phases, phase p:
//   { ds_read a-frags rows 2p,2p+1 (+ all b-frags at p0) from buf c;
//     stage one half-tile of tile i+1 into buf c^1 (2 gload_lds/thread);
//     s_barrier; setprio(1); 16 MFMA; setprio(0);
//     [p==3: s_waitcnt vmcnt(0) + "memory" fence]; s_barrier }
// Correctness: reads touch buf c only, stages touch buf c^1 only -> no
// intra-tile hazard; the p3 vmcnt(0)+barrier makes tile i+1 globally visible
// before any wave reads it, and buf c is only overwritten a full tile later
// behind that collective barrier. Per-phase barriers are pacing (keep waves
// clustered so staged halves get 1-3 phases of MFMA latency cover vs the
// m97-structure's zero-cover drain -> MfmaUtil 23% there).
// Accumulation order over K is IDENTICAL to gemm_bt -> bit-identical output.
__global__ __launch_bounds__(512) void gemm256(const unsigned short* __restrict__ A,
                                               const unsigned short* __restrict__ Bt,
                                               const float* __restrict__ b0,
                                               const float* __restrict__ b1,
                                               const float* __restrict__ b2,
                                               int s1, int s2,
                                               unsigned short* __restrict__ C,
                                               int M, int N, int K) {
    __shared__ unsigned short As[2][256 * 64];   // 64 KB
    __shared__ unsigned short Bs[2][256 * 64];   // 64 KB
    const int t = threadIdx.x;
    const int lane = t & 63;
    const int wave = t >> 6;                     // 0..7
    const int qlane = lane & 15;
    const int quad = lane >> 4;
    const int wm = (wave >> 2) * 128;            // 2 M-rows of waves
    const int wn = (wave & 3) * 64;              // 4 N-cols of waves
    const int bm = blockIdx.y * 256;
    const int bn = blockIdx.x * 256;
    const int rsw = 2 * (qlane >> 2);

    floatx4 acc[8][4] = {};
    const int nt = K / 64;

    // prologue: stage tile 0 (4 half-tiles) into buf 0, full drain
    stage_half(A  + (size_t)bm * K,         &As[0][0],        t, K);
    stage_half(A  + (size_t)(bm + 128) * K, &As[0][128 * 64], t, K);
    stage_half(Bt + (size_t)bn * K,         &Bs[0][0],        t, K);
    stage_half(Bt + (size_t)(bn + 128) * K, &Bs[0][128 * 64], t, K);
    __syncthreads();

    for (int i = 0; i < nt; ++i) {
        const int c = i & 1, nx = c ^ 1;
        const size_t k1 = (size_t)(i + 1) * 64;

        // b-frags for the whole K-tile (reused across all 4 phases)
        short8 b[4][2];
#pragma unroll
        for (int fc = 0; fc < 4; ++fc)
#pragma unroll
            for (int kk = 0; kk < 2; ++kk)
                b[fc][kk] = *(const short8*)&Bs[c][(wn + fc * 16 + qlane) * 64 + ((kk * 4 + quad) ^ rsw) * 8];

#pragma unroll
        for (int p = 0; p < 4; ++p) {
            short8 a[2][2];
#pragma unroll
            for (int d = 0; d < 2; ++d)
#pragma unroll
                for (int kk = 0; kk < 2; ++kk)
                    a[d][kk] = *(const short8*)&As[c][(wm + (2 * p + d) * 16 + qlane) * 64 + ((kk * 4 + quad) ^ rsw) * 8];

            if (i + 1 < nt) {
                if (p == 0) stage_half(A  + (size_t)bm * K + k1,         &As[nx][0],        t, K);
                if (p == 1) stage_half(A  + (size_t)(bm + 128) * K + k1, &As[nx][128 * 64], t, K);
                if (p == 2) stage_half(Bt + (size_t)bn * K + k1,         &Bs[nx][0],        t, K);
                if (p == 3) stage_half(Bt + (size_t)(bn + 128) * K + k1, &Bs[nx][128 * 64], t, K);
            }

            __builtin_amdgcn_s_barrier();
            __builtin_amdgcn_s_setprio(1);
#pragma unroll
            for (int d = 0; d < 2; ++d)
#pragma unroll
                for (int fc = 0; fc < 4; ++fc)
#pragma unroll
                    for (int kk = 0; kk < 2; ++kk)
                        acc[2 * p + d][fc] = MFMA(a[d][kk], b[fc][kk], acc[2 * p + d][fc]);
            __builtin_amdgcn_s_setprio(0);
            if (p == 3) asm volatile("s_waitcnt vmcnt(0)" ::: "memory");
            __builtin_amdgcn_s_barrier();
        }
    }

    // epilogue: bias (3-way split) + f2bf store
#pragma unroll
    for (int fc = 0; fc < 4; ++fc) {
        int col = bn + wn + fc * 16 + qlane;
        int cc = col; const float* bp = b0;
        if (col >= s2)      { bp = b2; cc = col - s2; }
        else if (col >= s1) { bp = b1; cc = col - s1; }
        float bvv = bp[cc];
#pragma unroll
        for (int fr = 0; fr < 8; ++fr) {
            int row0 = bm + wm + fr * 16 + quad * 4;
#pragma unroll
            for (int r = 0; r < 4; ++r)
                C[(size_t)(row0 + r) * N + col] = f2bf(acc[fr][fc][r] + bvv);
        }
    }
}

// ---------------- Flash attention (128-row Q tiles, 32 rows/wave) ------------
// R10-proven: two-barrier staging + swapped QK^T + register-P (cvt_pk) +
// key-permuted V + pre-scaled mask. Unchanged this round.
__global__ __launch_bounds__(256, 4) void attn_kernel(const unsigned short* __restrict__ qkv,
                                                      const unsigned short* __restrict__ vtb,
                                                      const float* __restrict__ mw,
                                                      unsigned short* __restrict__ ob) {
    const int qt = blockIdx.x;
    const int head = blockIdx.y;
    const int b = blockIdx.z;
    const int kvh = head >> 2;
    const int qcol = head * 64;
    const int kcol = 2048 + kvh * 64;   // K slice inside qkv row
    const int vch = kvh * 64;           // Vt channel base
    const int q0 = qt * 128;
    const int t = threadIdx.x;
    const int lane = t & 63;
    const int wave = t >> 6;
    const int qlane = lane & 15;
    const int quad = lane >> 4;
    const int wr = wave * 32;

    __shared__ unsigned short Ks[64 * 64];      //  8 KB (single)
    __shared__ unsigned short Vts[2][64 * 64];  // 16 KB (double buffer)

    const int gc8 = (((t & 7) ^ (2 * ((t >> 5) & 3))) * 8);  // swizzled global chunk
    const int rsw = 2 * (qlane >> 2);                        // read-side swizzle
    const float scale2 = 0.125f * LOG2E;

    const unsigned short* vbase = vtb + (size_t)(b * 512 + vch) * S_;
    const float* mbase = mw + (size_t)b * S_;

    short8 aq[2][2];
#pragma unroll
    for (int mi = 0; mi < 2; ++mi)
#pragma unroll
        for (int kk = 0; kk < 2; ++kk)
            aq[mi][kk] = *(const short8*)(qkv +
                (size_t)(b * S_ + q0 + wr + mi * 16 + qlane) * 3072 + qcol + kk * 32 + quad * 8);

    {
        int row = t >> 3;
#pragma unroll
        for (int i = 0; i < 2; ++i) {
            int rr = row + 32 * i;
            gload_lds16(qkv + (size_t)(b * S_ + rr) * 3072 + kcol + gc8,
                        &Ks[(rr * 8 + (t & 7)) * 8]);
            gload_lds16(vbase + (size_t)rr * S_ + gc8,
                        &Vts[0][(rr * 8 + (t & 7)) * 8]);
        }
    }

    short8 ones;
    {
        short v = (qlane == 0) ? (short)0x3F80 : (short)0;
        ones = (short8){v, v, v, v, v, v, v, v};
    }

    floatx4 o[2][4] = {};
    floatx4 osum[2] = {};

    __syncthreads();

    for (int kt = 0; kt < 32; ++kt) {
        const int cur = kt & 1;

        if (kt < 31) {
            const int nxt = cur ^ 1;
            int kn = (kt + 1) * 64;
            int row = t >> 3;
#pragma unroll
            for (int i = 0; i < 2; ++i) {
                int rr = row + 32 * i;
                gload_lds16(vbase + (size_t)rr * S_ + kn + gc8,
                            &Vts[nxt][(rr * 8 + (t & 7)) * 8]);
            }
        }

        unsigned int pk[2][4][2];
#pragma unroll
        for (int jj = 0; jj < 4; jj += 2) {
            floatx4 st[2][2] = {};
            __builtin_amdgcn_s_setprio(1);
#pragma unroll
            for (int dj = 0; dj < 2; ++dj) {
                int j = jj + dj;
                short8 bk0 = *(const short8*)&Ks[(j * 16 + qlane) * 64 + ((0 + quad) ^ rsw) * 8];
                short8 bk1 = *(const short8*)&Ks[(j * 16 + qlane) * 64 + ((4 + quad) ^ rsw) * 8];
#pragma unroll
                for (int mi = 0; mi < 2; ++mi) {
                    st[dj][mi] = MFMA(bk0, aq[mi][0], st[dj][mi]);
                    st[dj][mi] = MFMA(bk1, aq[mi][1], st[dj][mi]);
                }
            }
            __builtin_amdgcn_s_setprio(0);
#pragma unroll
            for (int dj = 0; dj < 2; ++dj) {
                int j = jj + dj;
                floatx4 mv = *(const floatx4*)(mbase + kt * 64 + j * 16 + quad * 4);
#pragma unroll
                for (int mi = 0; mi < 2; ++mi)
#pragma unroll
                    for (int h = 0; h < 2; ++h) {
                        float p0 = __builtin_amdgcn_exp2f(st[dj][mi][2 * h]     * scale2 + mv[2 * h]);
                        float p1 = __builtin_amdgcn_exp2f(st[dj][mi][2 * h + 1] * scale2 + mv[2 * h + 1]);
                        unsigned int r;
                        asm("v_cvt_pk_bf16_f32 %0, %1, %2" : "=v"(r) : "v"(p0), "v"(p1));
                        pk[mi][j][h] = r;  // lo = key 2h, hi = key 2h+1
                    }
            }
        }

        __syncthreads();

        if (kt < 31) {
            int kn = (kt + 1) * 64;
            int row = t >> 3;
#pragma unroll
            for (int i = 0; i < 2; ++i) {
                int rr = row + 32 * i;
                gload_lds16(qkv + (size_t)(b * S_ + kn + rr) * 3072 + kcol + gc8,
                            &Ks[(rr * 8 + (t & 7)) * 8]);
            }
        }

        __builtin_amdgcn_s_setprio(1);
#pragma unroll
        for (int kk = 0; kk < 2; ++kk) {
            short8 ap[2];
#pragma unroll
            for (int mi = 0; mi < 2; ++mi) {
                uintx4 u = {pk[mi][2 * kk][0], pk[mi][2 * kk][1],
                            pk[mi][2 * kk + 1][0], pk[mi][2 * kk + 1][1]};
                ap[mi] = __builtin_bit_cast(short8, u);
            }
#pragma unroll
            for (int j2 = 0; j2 < 4; ++j2) {
                short8 bv = *(const short8*)&Vts[cur][(j2 * 16 + qlane) * 64 + ((kk * 4 + quad) ^ rsw) * 8];
#pragma unroll
                for (int mi = 0; mi < 2; ++mi)
                    o[mi][j2] = MFMA(ap[mi], bv, o[mi][j2]);
            }
#pragma unroll
            for (int mi = 0; mi < 2; ++mi)
                osum[mi] = MFMA(ap[mi], ones, osum[mi]);
        }
        __builtin_amdgcn_s_setprio(0);

        __syncthreads();
    }

#pragma unroll
    for (int mi = 0; mi < 2; ++mi)
#pragma unroll
        for (int r = 0; r < 4; ++r) {
            float sm = __shfl(osum[mi][r], quad * 16, 64);
            float inv = 1.0f / sm;
            int row = q0 + wr + mi * 16 + quad * 4 + r;
#pragma unroll
            for (int j2 = 0; j2 < 4; ++j2)
                ob[(size_t)(b * S_ + row) * H_ + qcol + j2 * 16 + qlane] = f2bf(o[mi][j2][r] * inv);
        }
}

extern "C" void kernel_launch(void* const* d_in, const int* in_sizes, int n_in,
                              void* d_out, int out_size, void* d_ws, size_t ws_size,
                              hipStream_t stream) {
    const float* x    = (const float*)d_in[0];
    const float* mask = (const float*)d_in[1];
    const float* Wq   = (const float*)d_in[2];
    const float* bq   = (const float*)d_in[3];
    const float* Wk   = (const float*)d_in[4];
    const float* bk   = (const float*)d_in[5];
    const float* Wv   = (const float*)d_in[6];
    const float* bv   = (const float*)d_in[7];
    const float* Wo   = (const float*)d_in[8];
    const float* bo   = (const float*)d_in[9];
    float* out = (float*)d_out;

    unsigned short* ws = (unsigned short*)d_ws;
    unsigned short* x_bf   = ws;
    unsigned short* qkv    = x_bf + (size_t)4096 * 2048;
    unsigned short* vt_buf = qkv + (size_t)4096 * 3072;
    unsigned short* WqkvT  = vt_buf + (size_t)2 * 512 * 2048;
    unsigned short* WoT    = WqkvT;           // aliased: Wo transposed after QKV GEMM
    unsigned short* a_buf  = x_bf;            // aliased: x consumed by QKV GEMM

    // pre-scaled mask (mask * LOG2E), parked in the TAIL of d_out
    float* mw = out + (size_t)4096 * 2048 - B_ * S_;

    const int BIG = 1 << 30;
    dim3 blk(256);
    // x -> bf16 (+1 block: mask pre-scale into mw)
    conv_f2b<<<dim3(4096 * 2048 / 4 / 256 + 1), blk, 0, stream>>>(x, x_bf, 4096 * 2048 / 4,
                                                                  mask, mw);
    // Wq|Wk|Wv -> WqkvT [3072][2048] (one launch)
    tr_wqkv<<<dim3(96, 64), blk, 0, stream>>>(Wq, Wk, Wv, WqkvT);
    // fused QKV projection: 256^2-tile 8-wave pipelined GEMM
    gemm256<<<dim3(12, 16), dim3(512), 0, stream>>>(x_bf, WqkvT, bq, bk, bv, 2048, 2560,
                                                    qkv, 4096, 3072, 2048);
    // Wo -> WoT (into WqkvT's space, now dead)
    tr_f2b<<<dim3(64, 64), blk, 0, stream>>>(Wo, WoT, 2048, 2048);
    // per-batch V transpose with key permutation: qkv[b][s][2560..] -> vt[b][512][S]
    tr_vperm<<<dim3(16, 64, 2), blk, 0, stream>>>(qkv + 2560, vt_buf, 2048, 512, 3072,
                                                  (size_t)2048 * 3072, (size_t)512 * 2048);
    // attention (reads mw, writes a_buf = x_bf)
    attn_kernel<<<dim3(16, 32, 2), blk, 0, stream>>>(qkv, vt_buf, mw, a_buf);
    // output projection (f32 out; overwrites mw region last)
    gemm_bt<true><<<dim3(16, 32), blk, 0, stream>>>(a_buf, WoT, bo, bo, bo, BIG, BIG,
                                                    out, 4096, 2048, 2048);
}